// Round 2
// baseline (112.920 us; speedup 1.0000x reference)
//
#include <hip/hip_runtime.h>
#include <hip/hip_bf16.h>
#include <math.h>

#define NN 4096
#define BB 8
#define CC 128
#define EE 131072
#define M_ROWS (BB*NN)      // 32768
#define DEG_CAP 512

typedef __attribute__((ext_vector_type(8))) short short8;
typedef __attribute__((ext_vector_type(4))) float f32x4;

__device__ __forceinline__ float bf2f(unsigned int u){
    union { unsigned int i; float f; } v; v.i = u << 16; return v.f;
}
__device__ __forceinline__ unsigned short f2bf(float f){
    union { float f; unsigned int i; } v; v.f = f;
    unsigned int u = v.i;
    unsigned int r = u + 0x7FFFu + ((u >> 16) & 1u);
    return (unsigned short)(r >> 16);
}

// ---- convert x (f32) -> bf16, 4 elems/thread ----
__global__ __launch_bounds__(256) void k_conv_x(const float* __restrict__ x,
                                                unsigned short* __restrict__ xbf, int n4){
    int i = blockIdx.x * blockDim.x + threadIdx.x;
    if (i < n4){
        float4 v = ((const float4*)x)[i];
        ushort4 o;
        o.x = f2bf(v.x); o.y = f2bf(v.y); o.z = f2bf(v.z); o.w = f2bf(v.w);
        ((ushort4*)xbf)[i] = o;
    }
}

// ---- transpose+convert weights: Wt[n][k] = W[k][n] as bf16 ----
__global__ __launch_bounds__(256) void k_prep_w(const float* __restrict__ W0, const float* __restrict__ W1,
                                                const float* __restrict__ W2, const float* __restrict__ Wo,
                                                unsigned short* __restrict__ Wt0, unsigned short* __restrict__ Wt1a,
                                                unsigned short* __restrict__ Wt1b, unsigned short* __restrict__ Wt2,
                                                unsigned short* __restrict__ Wto){
    int idx = blockIdx.x * blockDim.x + threadIdx.x;   // 0..81919
    int s = idx >> 14;
    int e = idx & 16383;
    int n = e >> 7, k = e & 127;
    float v; unsigned short* dst;
    switch (s){
        case 0:  v = W0[k*128+n];        dst = Wt0;  break;
        case 1:  v = W1[k*128+n];        dst = Wt1a; break;
        case 2:  v = W1[(128+k)*128+n];  dst = Wt1b; break;
        case 3:  v = W2[k*128+n];        dst = Wt2;  break;
        default: v = Wo[k*128+n];        dst = Wto;  break;
    }
    dst[n*128+k] = f2bf(v);
}

// ---- scatter edges into dense byte adjacency (idempotent stores, dedup free) ----
__global__ __launch_bounds__(256) void k_scatter(const int* __restrict__ ei,
                                                 unsigned char* __restrict__ adj){
    int e = blockIdx.x * blockDim.x + threadIdx.x;
    if (e < EE){
        int u = ei[e], v = ei[EE + e];
        adj[(size_t)u * NN + v] = 1;
        adj[(size_t)v * NN + u] = 1;
    }
}

// ---- compact adjacency row -> padded CSR (skip diagonal) ----
__global__ __launch_bounds__(256) void k_csr(const unsigned char* __restrict__ adj,
                                             int* __restrict__ cols, int* __restrict__ deg){
    __shared__ int sc[256];
    int i = blockIdx.x, t = threadIdx.x;
    uint4 w = *((const uint4*)(adj + (size_t)i * NN + t * 16));
    unsigned char b[16]; *((uint4*)b) = w;
    int c = 0;
    #pragma unroll
    for (int q = 0; q < 16; q++){ int j = t*16 + q; if (b[q] && j != i) c++; }
    sc[t] = c; __syncthreads();
    int val = c;
    for (int off = 1; off < 256; off <<= 1){
        int add = (t >= off) ? sc[t - off] : 0;
        __syncthreads();
        val += add; sc[t] = val;
        __syncthreads();
    }
    int total = sc[255];
    int pos = val - c;   // exclusive prefix
    #pragma unroll
    for (int q = 0; q < 16; q++){
        int j = t*16 + q;
        if (b[q] && j != i){
            if (pos < DEG_CAP) cols[(size_t)i * DEG_CAP + pos] = j;
            pos++;
        }
    }
    if (t == 0) deg[i] = total < DEG_CAP ? total : DEG_CAP;
}

// ---- sparse aggregation: agg[b,i,:] = sum_{j in N(i)} h[b,j,:] ----
// hT layout: [j][b*128+d] bf16 (2KB contiguous per j). Block per i, 256 thr, 4 elems/thr.
__global__ __launch_bounds__(256) void k_agg(const unsigned short* __restrict__ hT,
                                             const int* __restrict__ cols,
                                             const int* __restrict__ deg,
                                             unsigned short* __restrict__ aggbf){
    int i = blockIdx.x, t = threadIdx.x;
    int d = deg[i];
    const int* cl = cols + (size_t)i * DEG_CAP;
    float a0 = 0.f, a1 = 0.f, a2 = 0.f, a3 = 0.f;
    int n = 0;
    for (; n + 1 < d; n += 2){
        int j0 = cl[n], j1 = cl[n+1];
        uint2 u0 = *((const uint2*)(hT + (size_t)j0 * 1024 + t * 4));
        uint2 u1 = *((const uint2*)(hT + (size_t)j1 * 1024 + t * 4));
        a0 += bf2f(u0.x & 0xFFFFu) + bf2f(u1.x & 0xFFFFu);
        a1 += bf2f(u0.x >> 16)     + bf2f(u1.x >> 16);
        a2 += bf2f(u0.y & 0xFFFFu) + bf2f(u1.y & 0xFFFFu);
        a3 += bf2f(u0.y >> 16)     + bf2f(u1.y >> 16);
    }
    if (n < d){
        int j0 = cl[n];
        uint2 u0 = *((const uint2*)(hT + (size_t)j0 * 1024 + t * 4));
        a0 += bf2f(u0.x & 0xFFFFu);
        a1 += bf2f(u0.x >> 16);
        a2 += bf2f(u0.y & 0xFFFFu);
        a3 += bf2f(u0.y >> 16);
    }
    int b  = t >> 5;
    int ch = (t & 31) * 4;
    ushort4 o; o.x = f2bf(a0); o.y = f2bf(a1); o.z = f2bf(a2); o.w = f2bf(a3);
    *((ushort4*)(aggbf + (size_t)b * (NN*128) + (size_t)i * 128 + ch)) = o;
}

// ---- bf16 MFMA GEMM: [32768,128] x [128,128] (+bias/addC/gelu/resid) ----
template<bool TRANS_OUT, bool HAS_BIAS, bool HAS_ADDC, bool DO_GELU, bool HAS_RESID, bool OUT_BF16>
__global__ __launch_bounds__(256) void k_gemm(const unsigned short* __restrict__ A,
                                              const unsigned short* __restrict__ Wt,
                                              const float* __restrict__ bias,
                                              const float* __restrict__ addC,
                                              const float* __restrict__ resid,
                                              void* __restrict__ out){
    __shared__ unsigned short As[128*128];
    __shared__ unsigned short Ws[128*128];
    const int t = threadIdx.x;
    const int blockRow = blockIdx.x * 128;

    // stage A tile + full weight with XOR swizzle (16B granules).
    // 8 iters x 256 thr x 8 bf16 = 16384 elements each for A and W.
    #pragma unroll
    for (int it = 0; it < 8; ++it){
        int g = it * 2048 + t * 8;
        int r = g >> 7;            // 0..127
        int k = g & 127;
        int byte = r * 256 + ((k * 2) ^ ((r & 7) << 4));
        uint4 av = *((const uint4*)(A + (size_t)(blockRow + r) * 128 + k));
        *((uint4*)((char*)As + byte)) = av;
        uint4 wv = *((const uint4*)(Wt + r * 128 + k));
        *((uint4*)((char*)Ws + byte)) = wv;
    }
    __syncthreads();

    const int lane = t & 63;
    const int w  = t >> 6;
    const int wr = (w >> 1) * 64;
    const int wc = (w & 1) * 64;
    const int l15 = lane & 15;
    const int lh  = lane >> 4;

    f32x4 acc[4][4];
    #pragma unroll
    for (int m = 0; m < 4; m++)
        #pragma unroll
        for (int n = 0; n < 4; n++) acc[m][n] = (f32x4)(0.0f);

    #pragma unroll
    for (int ks = 0; ks < 4; ++ks){
        const int kc = ks * 32 + lh * 8;   // k-chunk start (8 contiguous bf16)
        short8 af[4], bf[4];
        #pragma unroll
        for (int m = 0; m < 4; m++){
            int r = wr + m * 16 + l15;
            int byte = r * 256 + ((kc * 2) ^ ((r & 7) << 4));
            af[m] = *((const short8*)((const char*)As + byte));
        }
        #pragma unroll
        for (int n = 0; n < 4; n++){
            int r = wc + n * 16 + l15;
            int byte = r * 256 + ((kc * 2) ^ ((r & 7) << 4));
            bf[n] = *((const short8*)((const char*)Ws + byte));
        }
        #pragma unroll
        for (int m = 0; m < 4; m++)
            #pragma unroll
            for (int n = 0; n < 4; n++)
                acc[m][n] = __builtin_amdgcn_mfma_f32_16x16x32_bf16(af[m], bf[n], acc[m][n], 0, 0, 0);
    }

    // epilogue
    #pragma unroll
    for (int m = 0; m < 4; m++){
        #pragma unroll
        for (int r = 0; r < 4; r++){
            int row = blockRow + wr + m * 16 + lh * 4 + r;
            #pragma unroll
            for (int n = 0; n < 4; n++){
                int col = wc + n * 16 + l15;
                float v = acc[m][n][r];
                if (HAS_BIAS)  v += bias[col];
                if (HAS_ADDC)  v += addC[(size_t)row * 128 + col];
                if (DO_GELU)   v = 0.5f * v * (1.0f + erff(v * 0.70710678118f));
                if (HAS_RESID) v += resid[(size_t)row * 128 + col];
                if (OUT_BF16){
                    unsigned short* o = (unsigned short*)out;
                    if (TRANS_OUT){
                        int b_ = row >> 12, j = row & 4095;
                        o[(size_t)j * 1024 + b_ * 128 + col] = f2bf(v);
                    } else {
                        o[(size_t)row * 128 + col] = f2bf(v);
                    }
                } else {
                    ((float*)out)[(size_t)row * 128 + col] = v;
                }
            }
        }
    }
}

extern "C" void kernel_launch(void* const* d_in, const int* in_sizes, int n_in,
                              void* d_out, int out_size, void* d_ws, size_t ws_size,
                              hipStream_t stream) {
    const float* x  = (const float*)d_in[0];
    const int*   ei = (const int*)d_in[1];
    const float* W0 = (const float*)d_in[2];
    const float* b0 = (const float*)d_in[3];
    const float* W1 = (const float*)d_in[4];
    const float* b1 = (const float*)d_in[5];
    const float* W2 = (const float*)d_in[6];
    const float* b2 = (const float*)d_in[7];
    const float* Wo = (const float*)d_in[8];
    const float* bo = (const float*)d_in[9];
    float* out = (float*)d_out;

    char* ws = (char*)d_ws;
    unsigned char* adj   = (unsigned char*)(ws + 0);                 // 16777216
    int*   cols          = (int*)(ws + 16777216);                    // 8388608
    int*   deg           = (int*)(ws + 25165824);                    // 16384
    unsigned short* xbf  = (unsigned short*)(ws + 25182208);         // 8388608
    unsigned short* hT   = (unsigned short*)(ws + 33570816);         // 8388608
    unsigned short* aggb = (unsigned short*)(ws + 41959424);         // 8388608
    float* t1            = (float*)(ws + 50348032);                  // 16777216
    unsigned short* t1bf = (unsigned short*)(ws + 67125248);         // 8388608
    unsigned short* gbf  = (unsigned short*)(ws + 75513856);         // 8388608
    unsigned short* Wt0  = (unsigned short*)(ws + 83902464);
    unsigned short* Wt1a = (unsigned short*)(ws + 83902464 + 32768);
    unsigned short* Wt1b = (unsigned short*)(ws + 83902464 + 65536);
    unsigned short* Wt2  = (unsigned short*)(ws + 83902464 + 98304);
    unsigned short* Wto  = (unsigned short*)(ws + 83902464 + 131072);

    hipMemsetAsync(adj, 0, (size_t)NN * NN, stream);

    k_conv_x<<<4096, 256, 0, stream>>>(x, xbf, M_ROWS * 128 / 4);
    k_prep_w<<<320, 256, 0, stream>>>(W0, W1, W2, Wo, Wt0, Wt1a, Wt1b, Wt2, Wto);
    k_scatter<<<EE / 256, 256, 0, stream>>>(ei, adj);
    k_csr<<<NN, 256, 0, stream>>>(adj, cols, deg);

    // h = x@W0 + b0  -> hT (transposed bf16 [j][b*128+d])
    k_gemm<true, true, false, false, false, true><<<256, 256, 0, stream>>>(xbf, Wt0, b0, nullptr, nullptr, hT);
    // agg
    k_agg<<<NN, 256, 0, stream>>>(hT, cols, deg, aggb);
    // t1 = x@W1a + b1 (f32)
    k_gemm<false, true, false, false, false, false><<<256, 256, 0, stream>>>(xbf, Wt1a, b1, nullptr, nullptr, t1);
    // t1bf = agg@W1b + t1 (bf16)
    k_gemm<false, false, true, false, false, true><<<256, 256, 0, stream>>>(aggb, Wt1b, nullptr, t1, nullptr, t1bf);
    // gbf = gelu(t1bf@W2 + b2) (bf16)
    k_gemm<false, true, false, true, false, true><<<256, 256, 0, stream>>>(t1bf, Wt2, b2, nullptr, nullptr, gbf);
    // out = gbf@Wo + bo + x (f32)
    k_gemm<false, true, false, false, true, false><<<256, 256, 0, stream>>>(gbf, Wto, bo, nullptr, x, out);
}

// Round 3
// 93.800 us; speedup vs baseline: 1.2038x; 1.2038x over previous
//
#include <hip/hip_runtime.h>
#include <hip/hip_bf16.h>
#include <math.h>

#define NN 4096
#define BB 8
#define CC 128
#define EE 131072
#define M_ROWS (BB*NN)      // 32768
#define DEG_CAP 512

typedef __attribute__((ext_vector_type(8))) short short8;
typedef __attribute__((ext_vector_type(4))) float f32x4;

__device__ __forceinline__ float bf2f(unsigned int u){
    union { unsigned int i; float f; } v; v.i = u << 16; return v.f;
}
__device__ __forceinline__ unsigned short f2bf(float f){
    union { float f; unsigned int i; } v; v.f = f;
    unsigned int u = v.i;
    unsigned int r = u + 0x7FFFu + ((u >> 16) & 1u);
    return (unsigned short)(r >> 16);
}

// swizzled byte offset for element (row r, k) in a [rows][128] bf16 LDS tile (256B rows)
__device__ __forceinline__ int swz(int r, int k2 /*byte offset in row*/){
    return r * 256 + (k2 ^ ((r & 7) << 4));
}

// ---- transpose+convert weights: Wt[n][k] = W[k][n] as bf16 ----
__global__ __launch_bounds__(256) void k_prep_w(const float* __restrict__ W0, const float* __restrict__ W1,
                                                const float* __restrict__ W2, const float* __restrict__ Wo,
                                                unsigned short* __restrict__ Wt0, unsigned short* __restrict__ Wt1a,
                                                unsigned short* __restrict__ Wt1b, unsigned short* __restrict__ Wt2,
                                                unsigned short* __restrict__ Wto){
    int idx = blockIdx.x * blockDim.x + threadIdx.x;   // 0..81919
    int s = idx >> 14;
    int e = idx & 16383;
    int n = e >> 7, k = e & 127;
    float v; unsigned short* dst;
    switch (s){
        case 0:  v = W0[k*128+n];        dst = Wt0;  break;
        case 1:  v = W1[k*128+n];        dst = Wt1a; break;
        case 2:  v = W1[(128+k)*128+n];  dst = Wt1b; break;
        case 3:  v = W2[k*128+n];        dst = Wt2;  break;
        default: v = Wo[k*128+n];        dst = Wto;  break;
    }
    dst[n*128+k] = f2bf(v);
}

// ---- scatter edges into dense byte adjacency (idempotent stores, dedup free) ----
__global__ __launch_bounds__(256) void k_scatter(const int* __restrict__ ei,
                                                 unsigned char* __restrict__ adj){
    int e = blockIdx.x * blockDim.x + threadIdx.x;
    if (e < EE){
        int u = ei[e], v = ei[EE + e];
        adj[(size_t)u * NN + v] = 1;
        adj[(size_t)v * NN + u] = 1;
    }
}

// ---- compact adjacency row -> padded CSR (skip diagonal) ----
__global__ __launch_bounds__(256) void k_csr(const unsigned char* __restrict__ adj,
                                             int* __restrict__ cols, int* __restrict__ deg){
    __shared__ int sc[256];
    int i = blockIdx.x, t = threadIdx.x;
    uint4 w = *((const uint4*)(adj + (size_t)i * NN + t * 16));
    unsigned char b[16]; *((uint4*)b) = w;
    int c = 0;
    #pragma unroll
    for (int q = 0; q < 16; q++){ int j = t*16 + q; if (b[q] && j != i) c++; }
    sc[t] = c; __syncthreads();
    int val = c;
    for (int off = 1; off < 256; off <<= 1){
        int add = (t >= off) ? sc[t - off] : 0;
        __syncthreads();
        val += add; sc[t] = val;
        __syncthreads();
    }
    int total = sc[255];
    int pos = val - c;   // exclusive prefix
    #pragma unroll
    for (int q = 0; q < 16; q++){
        int j = t*16 + q;
        if (b[q] && j != i){
            if (pos < DEG_CAP) cols[(size_t)i * DEG_CAP + pos] = j;
            pos++;
        }
    }
    if (t == 0) deg[i] = total < DEG_CAP ? total : DEG_CAP;
}

// ---- sparse aggregation, unroll-4: agg[b,i,:] = sum_{j in N(i)} h[b,j,:] ----
// hT layout: [j][b*128+d] bf16 (2KB contiguous per j). Block per i, 256 thr, 4 elems/thr.
__global__ __launch_bounds__(256) void k_agg(const unsigned short* __restrict__ hT,
                                             const int* __restrict__ cols,
                                             const int* __restrict__ deg,
                                             unsigned short* __restrict__ aggbf){
    int i = blockIdx.x, t = threadIdx.x;
    int d = deg[i];
    const int* cl = cols + (size_t)i * DEG_CAP;
    const unsigned short* hp = hT + t * 4;
    float a0 = 0.f, a1 = 0.f, a2 = 0.f, a3 = 0.f;
    int n = 0;
    for (; n + 3 < d; n += 4){
        int4 c = *((const int4*)(cl + n));
        uint2 u0 = *((const uint2*)(hp + ((size_t)c.x << 10)));
        uint2 u1 = *((const uint2*)(hp + ((size_t)c.y << 10)));
        uint2 u2 = *((const uint2*)(hp + ((size_t)c.z << 10)));
        uint2 u3 = *((const uint2*)(hp + ((size_t)c.w << 10)));
        a0 += bf2f(u0.x & 0xFFFFu) + bf2f(u1.x & 0xFFFFu) + bf2f(u2.x & 0xFFFFu) + bf2f(u3.x & 0xFFFFu);
        a1 += bf2f(u0.x >> 16)     + bf2f(u1.x >> 16)     + bf2f(u2.x >> 16)     + bf2f(u3.x >> 16);
        a2 += bf2f(u0.y & 0xFFFFu) + bf2f(u1.y & 0xFFFFu) + bf2f(u2.y & 0xFFFFu) + bf2f(u3.y & 0xFFFFu);
        a3 += bf2f(u0.y >> 16)     + bf2f(u1.y >> 16)     + bf2f(u2.y >> 16)     + bf2f(u3.y >> 16);
    }
    for (; n < d; ++n){
        int j0 = cl[n];
        uint2 u0 = *((const uint2*)(hp + ((size_t)j0 << 10)));
        a0 += bf2f(u0.x & 0xFFFFu);
        a1 += bf2f(u0.x >> 16);
        a2 += bf2f(u0.y & 0xFFFFu);
        a3 += bf2f(u0.y >> 16);
    }
    int b  = t >> 5;
    int ch = (t & 31) * 4;
    ushort4 o; o.x = f2bf(a0); o.y = f2bf(a1); o.z = f2bf(a2); o.w = f2bf(a3);
    *((ushort4*)(aggbf + (size_t)b * (NN*128) + (size_t)i * 128 + ch)) = o;
}

// ===== shared GEMM helpers (64-row tiles, 4 waves: 2x2 wave grid of 32x64) =====
// stage 64x128 bf16 tile from bf16 source rows [blockRow..+63]
__device__ __forceinline__ void stage_a_bf16(const unsigned short* __restrict__ src, int blockRow,
                                             unsigned short* As, int t){
    #pragma unroll
    for (int it = 0; it < 4; ++it){
        int g = it * 2048 + t * 8;
        int r = g >> 7, k = g & 127;
        uint4 v = *((const uint4*)(src + (size_t)(blockRow + r) * 128 + k));
        *((uint4*)((char*)As + swz(r, k * 2))) = v;
    }
}
// stage 64x128 tile from f32 source (convert to bf16)
__device__ __forceinline__ void stage_a_f32(const float* __restrict__ src, int blockRow,
                                            unsigned short* As, int t){
    #pragma unroll
    for (int it = 0; it < 4; ++it){
        int g = it * 2048 + t * 8;
        int r = g >> 7, k = g & 127;
        const float* p = src + (size_t)(blockRow + r) * 128 + k;
        float4 lo = *((const float4*)p);
        float4 hi = *((const float4*)(p + 4));
        ushort4 w0, w1;
        w0.x = f2bf(lo.x); w0.y = f2bf(lo.y); w0.z = f2bf(lo.z); w0.w = f2bf(lo.w);
        w1.x = f2bf(hi.x); w1.y = f2bf(hi.y); w1.z = f2bf(hi.z); w1.w = f2bf(hi.w);
        char* dst = (char*)As + swz(r, k * 2);
        *((ushort4*)dst) = w0;
        *((ushort4*)(dst + 8)) = w1;
    }
}
// stage 128x128 weight
__device__ __forceinline__ void stage_w(const unsigned short* __restrict__ Wt,
                                        unsigned short* Ws, int t){
    #pragma unroll
    for (int it = 0; it < 8; ++it){
        int g = it * 2048 + t * 8;
        int r = g >> 7, k = g & 127;
        uint4 v = *((const uint4*)(Wt + r * 128 + k));
        *((uint4*)((char*)Ws + swz(r, k * 2))) = v;
    }
}
// one K=128 pass: acc[2][4] += As(32x128 at wr) x Ws(64 cols at wc)
__device__ __forceinline__ void mfma_pass(const unsigned short* As, const unsigned short* Ws,
                                          int wr, int wc, int l15, int lh, f32x4 acc[2][4]){
    #pragma unroll
    for (int ks = 0; ks < 4; ++ks){
        const int kc = ks * 32 + lh * 8;
        short8 af[2], bfv[4];
        #pragma unroll
        for (int m = 0; m < 2; m++){
            int r = wr + m * 16 + l15;
            af[m] = *((const short8*)((const char*)As + swz(r, kc * 2)));
        }
        #pragma unroll
        for (int n = 0; n < 4; n++){
            int r = wc + n * 16 + l15;
            bfv[n] = *((const short8*)((const char*)Ws + swz(r, kc * 2)));
        }
        #pragma unroll
        for (int m = 0; m < 2; m++)
            #pragma unroll
            for (int n = 0; n < 4; n++)
                acc[m][n] = __builtin_amdgcn_mfma_f32_16x16x32_bf16(af[m], bfv[n], acc[m][n], 0, 0, 0);
    }
}

// ---- gemm0: hT = (x@W0 + b0) transposed to [j][b*128+col], x is f32 ----
__global__ __launch_bounds__(256) void k_gemm0(const float* __restrict__ x,
                                               const unsigned short* __restrict__ Wt0,
                                               const float* __restrict__ b0,
                                               unsigned short* __restrict__ hT){
    __shared__ unsigned short As[64*128];
    __shared__ unsigned short Ws[128*128];
    const int t = threadIdx.x;
    const int blockRow = blockIdx.x * 64;
    stage_a_f32(x, blockRow, As, t);
    stage_w(Wt0, Ws, t);
    __syncthreads();
    const int lane = t & 63, w = t >> 6;
    const int wr = (w >> 1) * 32, wc = (w & 1) * 64;
    const int l15 = lane & 15, lh = lane >> 4;
    f32x4 acc[2][4];
    #pragma unroll
    for (int m = 0; m < 2; m++) for (int n = 0; n < 4; n++) acc[m][n] = (f32x4)(0.0f);
    mfma_pass(As, Ws, wr, wc, l15, lh, acc);
    #pragma unroll
    for (int m = 0; m < 2; m++){
        #pragma unroll
        for (int rr = 0; rr < 4; rr++){
            int row = blockRow + wr + m * 16 + lh * 4 + rr;
            int b_ = row >> 12, j = row & 4095;
            #pragma unroll
            for (int n = 0; n < 4; n++){
                int col = wc + n * 16 + l15;
                float v = acc[m][n][rr] + b0[col];
                hT[(size_t)j * 1024 + b_ * 128 + col] = f2bf(v);
            }
        }
    }
}

// ---- gemm1: t1bf = x@W1a + agg@W1b + b1 (two K=128 phases) ----
__global__ __launch_bounds__(256) void k_gemm1(const float* __restrict__ x,
                                               const unsigned short* __restrict__ agg,
                                               const unsigned short* __restrict__ Wt1a,
                                               const unsigned short* __restrict__ Wt1b,
                                               const float* __restrict__ b1,
                                               unsigned short* __restrict__ t1bf){
    __shared__ unsigned short As[64*128];
    __shared__ unsigned short Ws[128*128];
    const int t = threadIdx.x;
    const int blockRow = blockIdx.x * 64;
    const int lane = t & 63, w = t >> 6;
    const int wr = (w >> 1) * 32, wc = (w & 1) * 64;
    const int l15 = lane & 15, lh = lane >> 4;
    f32x4 acc[2][4];
    #pragma unroll
    for (int m = 0; m < 2; m++) for (int n = 0; n < 4; n++) acc[m][n] = (f32x4)(0.0f);

    stage_a_f32(x, blockRow, As, t);
    stage_w(Wt1a, Ws, t);
    __syncthreads();
    mfma_pass(As, Ws, wr, wc, l15, lh, acc);
    __syncthreads();
    stage_a_bf16(agg, blockRow, As, t);
    stage_w(Wt1b, Ws, t);
    __syncthreads();
    mfma_pass(As, Ws, wr, wc, l15, lh, acc);

    #pragma unroll
    for (int m = 0; m < 2; m++){
        #pragma unroll
        for (int rr = 0; rr < 4; rr++){
            int row = blockRow + wr + m * 16 + lh * 4 + rr;
            #pragma unroll
            for (int n = 0; n < 4; n++){
                int col = wc + n * 16 + l15;
                float v = acc[m][n][rr] + b1[col];
                t1bf[(size_t)row * 128 + col] = f2bf(v);
            }
        }
    }
}

// ---- gemm23: out = gelu(t1bf@W2 + b2)@Wo + bo + x  (f32 out) ----
__global__ __launch_bounds__(256) void k_gemm23(const unsigned short* __restrict__ t1bf,
                                                const unsigned short* __restrict__ Wt2,
                                                const unsigned short* __restrict__ Wto,
                                                const float* __restrict__ b2,
                                                const float* __restrict__ bo,
                                                const float* __restrict__ x,
                                                float* __restrict__ out){
    __shared__ unsigned short As[64*128];     // reused: t1bf tile, then g tile
    __shared__ unsigned short Ws2[128*128];
    __shared__ unsigned short Wso[128*128];
    const int t = threadIdx.x;
    const int blockRow = blockIdx.x * 64;
    const int lane = t & 63, w = t >> 6;
    const int wr = (w >> 1) * 32, wc = (w & 1) * 64;
    const int l15 = lane & 15, lh = lane >> 4;

    stage_a_bf16(t1bf, blockRow, As, t);
    stage_w(Wt2, Ws2, t);
    stage_w(Wto, Wso, t);
    __syncthreads();

    f32x4 acc[2][4];
    #pragma unroll
    for (int m = 0; m < 2; m++) for (int n = 0; n < 4; n++) acc[m][n] = (f32x4)(0.0f);
    mfma_pass(As, Ws2, wr, wc, l15, lh, acc);
    __syncthreads();   // all waves done reading As

    // g = gelu(acc + b2) -> write bf16 back into As (swizzled, elementwise)
    #pragma unroll
    for (int m = 0; m < 2; m++){
        #pragma unroll
        for (int rr = 0; rr < 4; rr++){
            int rl = wr + m * 16 + lh * 4 + rr;   // local row
            #pragma unroll
            for (int n = 0; n < 4; n++){
                int col = wc + n * 16 + l15;
                float v = acc[m][n][rr] + b2[col];
                v = 0.5f * v * (1.0f + erff(v * 0.70710678118f));
                *((unsigned short*)((char*)As + swz(rl, col * 2))) = f2bf(v);
            }
        }
    }
    __syncthreads();

    f32x4 acc2[2][4];
    #pragma unroll
    for (int m = 0; m < 2; m++) for (int n = 0; n < 4; n++) acc2[m][n] = (f32x4)(0.0f);
    mfma_pass(As, Wso, wr, wc, l15, lh, acc2);

    #pragma unroll
    for (int m = 0; m < 2; m++){
        #pragma unroll
        for (int rr = 0; rr < 4; rr++){
            int row = blockRow + wr + m * 16 + lh * 4 + rr;
            #pragma unroll
            for (int n = 0; n < 4; n++){
                int col = wc + n * 16 + l15;
                float v = acc2[m][n][rr] + bo[col] + x[(size_t)row * 128 + col];
                out[(size_t)row * 128 + col] = v;
            }
        }
    }
}

extern "C" void kernel_launch(void* const* d_in, const int* in_sizes, int n_in,
                              void* d_out, int out_size, void* d_ws, size_t ws_size,
                              hipStream_t stream) {
    const float* x  = (const float*)d_in[0];
    const int*   ei = (const int*)d_in[1];
    const float* W0 = (const float*)d_in[2];
    const float* b0 = (const float*)d_in[3];
    const float* W1 = (const float*)d_in[4];
    const float* b1 = (const float*)d_in[5];
    const float* W2 = (const float*)d_in[6];
    const float* b2 = (const float*)d_in[7];
    const float* Wo = (const float*)d_in[8];
    const float* bo = (const float*)d_in[9];
    float* out = (float*)d_out;

    char* ws = (char*)d_ws;
    unsigned char* adj   = (unsigned char*)(ws + 0);                 // 16777216
    int*   cols          = (int*)(ws + 16777216);                    // 8388608
    int*   deg           = (int*)(ws + 25165824);                    // 16384
    unsigned short* hT   = (unsigned short*)(ws + 25182208);         // 8388608
    unsigned short* aggb = (unsigned short*)(ws + 33570816);         // 8388608
    unsigned short* t1bf = (unsigned short*)(ws + 41959424);         // 8388608
    unsigned short* Wt0  = (unsigned short*)(ws + 50348032);
    unsigned short* Wt1a = (unsigned short*)(ws + 50348032 + 32768);
    unsigned short* Wt1b = (unsigned short*)(ws + 50348032 + 65536);
    unsigned short* Wt2  = (unsigned short*)(ws + 50348032 + 98304);
    unsigned short* Wto  = (unsigned short*)(ws + 50348032 + 131072);

    hipMemsetAsync(adj, 0, (size_t)NN * NN, stream);

    k_prep_w<<<320, 256, 0, stream>>>(W0, W1, W2, Wo, Wt0, Wt1a, Wt1b, Wt2, Wto);
    k_scatter<<<EE / 256, 256, 0, stream>>>(ei, adj);
    k_csr<<<NN, 256, 0, stream>>>(adj, cols, deg);

    k_gemm0<<<M_ROWS / 64, 256, 0, stream>>>(x, Wt0, b0, hT);
    k_agg<<<NN, 256, 0, stream>>>(hT, cols, deg, aggb);
    k_gemm1<<<M_ROWS / 64, 256, 0, stream>>>(x, aggb, Wt1a, Wt1b, b1, t1bf);
    k_gemm23<<<M_ROWS / 64, 256, 0, stream>>>(t1bf, Wt2, Wto, b2, bo, x, out);
}

// Round 4
// 93.367 us; speedup vs baseline: 1.2094x; 1.0046x over previous
//
#include <hip/hip_runtime.h>
#include <hip/hip_bf16.h>
#include <math.h>

#define NN 4096
#define BB 8
#define CC 128
#define EE 131072
#define M_ROWS (BB*NN)      // 32768
#define DEG_CAP 512

typedef __attribute__((ext_vector_type(8))) short short8;
typedef __attribute__((ext_vector_type(4))) float f32x4;

__device__ __forceinline__ float bf2f(unsigned int u){
    union { unsigned int i; float f; } v; v.i = u << 16; return v.f;
}
__device__ __forceinline__ unsigned short f2bf(float f){
    union { float f; unsigned int i; } v; v.f = f;
    unsigned int u = v.i;
    unsigned int r = u + 0x7FFFu + ((u >> 16) & 1u);
    return (unsigned short)(r >> 16);
}

// swizzled byte offset for element (row r, k) in a [rows][128] bf16 LDS tile (256B rows)
__device__ __forceinline__ int swz(int r, int k2 /*byte offset in row*/){
    return r * 256 + (k2 ^ ((r & 7) << 4));
}

// ---- transpose+convert weights: Wt[n][k] = W[k][n] as bf16 ----
__global__ __launch_bounds__(256) void k_prep_w(const float* __restrict__ W0, const float* __restrict__ W1,
                                                const float* __restrict__ W2, const float* __restrict__ Wo,
                                                unsigned short* __restrict__ Wt0, unsigned short* __restrict__ Wt1a,
                                                unsigned short* __restrict__ Wt1b, unsigned short* __restrict__ Wt2,
                                                unsigned short* __restrict__ Wto){
    int idx = blockIdx.x * blockDim.x + threadIdx.x;   // 0..81919
    int s = idx >> 14;
    int e = idx & 16383;
    int n = e >> 7, k = e & 127;
    float v; unsigned short* dst;
    switch (s){
        case 0:  v = W0[k*128+n];        dst = Wt0;  break;
        case 1:  v = W1[k*128+n];        dst = Wt1a; break;
        case 2:  v = W1[(128+k)*128+n];  dst = Wt1b; break;
        case 3:  v = W2[k*128+n];        dst = Wt2;  break;
        default: v = Wo[k*128+n];        dst = Wto;  break;
    }
    dst[n*128+k] = f2bf(v);
}

// ---- scatter edges into bitmap adjacency (atomicOr, dedup free) ----
__global__ __launch_bounds__(256) void k_scatter(const int* __restrict__ ei,
                                                 unsigned int* __restrict__ bits){
    int e = blockIdx.x * blockDim.x + threadIdx.x;
    if (e < EE){
        int u = ei[e], v = ei[EE + e];
        atomicOr(&bits[u * 128 + (v >> 5)], 1u << (v & 31));
        atomicOr(&bits[v * 128 + (u >> 5)], 1u << (u & 31));
    }
}

// ---- compact bitmap row -> padded CSR (skip diagonal), 128 thr/block ----
__global__ __launch_bounds__(128) void k_csr(const unsigned int* __restrict__ bits,
                                             int* __restrict__ cols, int* __restrict__ deg){
    __shared__ int sc[128];
    int i = blockIdx.x, t = threadIdx.x;
    unsigned int w = bits[i * 128 + t];
    if (t == (i >> 5)) w &= ~(1u << (i & 31));   // zero diagonal
    int c = __popc(w);
    sc[t] = c; __syncthreads();
    int val = c;
    for (int off = 1; off < 128; off <<= 1){
        int add = (t >= off) ? sc[t - off] : 0;
        __syncthreads();
        val += add; sc[t] = val;
        __syncthreads();
    }
    int total = sc[127];
    int pos = val - c;   // exclusive prefix
    unsigned int ww = w;
    while (ww){
        int b = __ffs(ww) - 1;
        ww &= ww - 1;
        if (pos < DEG_CAP) cols[(size_t)i * DEG_CAP + pos] = t * 32 + b;
        pos++;
    }
    if (t == 0) deg[i] = total < DEG_CAP ? total : DEG_CAP;
}

// ---- sparse aggregation: agg[b,i,:] = sum_{j in N(i)} h[b,j,:] ----
// hT layout: [j][b*128+d] bf16 (2KB/row). Block per i; 128 lanes x 8ch (16B loads);
// two neighbor parity streams across thread halves; cols staged in LDS.
__device__ __forceinline__ void acc8(uint4 u, float* a){
    a[0] += bf2f(u.x & 0xFFFFu); a[1] += bf2f(u.x >> 16);
    a[2] += bf2f(u.y & 0xFFFFu); a[3] += bf2f(u.y >> 16);
    a[4] += bf2f(u.z & 0xFFFFu); a[5] += bf2f(u.z >> 16);
    a[6] += bf2f(u.w & 0xFFFFu); a[7] += bf2f(u.w >> 16);
}

__global__ __launch_bounds__(256) void k_agg(const unsigned short* __restrict__ hT,
                                             const int* __restrict__ cols,
                                             const int* __restrict__ deg,
                                             unsigned short* __restrict__ aggbf){
    __shared__ int scol[DEG_CAP];
    __shared__ float red[128][9];
    const int i = blockIdx.x, t = threadIdx.x;
    const int half = t >> 7, lane = t & 127;
    const int d = deg[i];
    const int* cl = cols + (size_t)i * DEG_CAP;
    for (int q = t; q < d; q += 256) scol[q] = cl[q];
    __syncthreads();

    const unsigned short* hp = hT + lane * 8;
    float a[8];
    #pragma unroll
    for (int c = 0; c < 8; c++) a[c] = 0.f;

    int n = half;
    for (; n + 6 < d; n += 8){
        int j0 = scol[n], j1 = scol[n+2], j2 = scol[n+4], j3 = scol[n+6];
        uint4 u0 = *((const uint4*)(hp + ((size_t)j0 << 10)));
        uint4 u1 = *((const uint4*)(hp + ((size_t)j1 << 10)));
        uint4 u2 = *((const uint4*)(hp + ((size_t)j2 << 10)));
        uint4 u3 = *((const uint4*)(hp + ((size_t)j3 << 10)));
        acc8(u0, a); acc8(u1, a); acc8(u2, a); acc8(u3, a);
    }
    for (; n < d; n += 2){
        uint4 u0 = *((const uint4*)(hp + ((size_t)scol[n] << 10)));
        acc8(u0, a);
    }

    if (half){
        #pragma unroll
        for (int c = 0; c < 8; c++) red[lane][c] = a[c];
    }
    __syncthreads();
    if (!half){
        #pragma unroll
        for (int c = 0; c < 8; c++) a[c] += red[lane][c];
        int b  = lane >> 4;
        int ch = (lane * 8) & 127;
        uint4 o;
        o.x = (unsigned)f2bf(a[0]) | ((unsigned)f2bf(a[1]) << 16);
        o.y = (unsigned)f2bf(a[2]) | ((unsigned)f2bf(a[3]) << 16);
        o.z = (unsigned)f2bf(a[4]) | ((unsigned)f2bf(a[5]) << 16);
        o.w = (unsigned)f2bf(a[6]) | ((unsigned)f2bf(a[7]) << 16);
        *((uint4*)(aggbf + (size_t)b * (NN*128) + (size_t)i * 128 + ch)) = o;
    }
}

// ===== shared GEMM helpers (64-row tiles, 4 waves: 2x2 wave grid of 32x64) =====
__device__ __forceinline__ void stage_a_bf16(const unsigned short* __restrict__ src, int blockRow,
                                             unsigned short* As, int t){
    #pragma unroll
    for (int it = 0; it < 4; ++it){
        int g = it * 2048 + t * 8;
        int r = g >> 7, k = g & 127;
        uint4 v = *((const uint4*)(src + (size_t)(blockRow + r) * 128 + k));
        *((uint4*)((char*)As + swz(r, k * 2))) = v;
    }
}
__device__ __forceinline__ void stage_a_f32(const float* __restrict__ src, int blockRow,
                                            unsigned short* As, int t){
    #pragma unroll
    for (int it = 0; it < 4; ++it){
        int g = it * 2048 + t * 8;
        int r = g >> 7, k = g & 127;
        const float* p = src + (size_t)(blockRow + r) * 128 + k;
        float4 lo = *((const float4*)p);
        float4 hi = *((const float4*)(p + 4));
        ushort4 w0, w1;
        w0.x = f2bf(lo.x); w0.y = f2bf(lo.y); w0.z = f2bf(lo.z); w0.w = f2bf(lo.w);
        w1.x = f2bf(hi.x); w1.y = f2bf(hi.y); w1.z = f2bf(hi.z); w1.w = f2bf(hi.w);
        char* dst = (char*)As + swz(r, k * 2);
        *((ushort4*)dst) = w0;
        *((ushort4*)(dst + 8)) = w1;
    }
}
__device__ __forceinline__ void stage_w(const unsigned short* __restrict__ Wt,
                                        unsigned short* Ws, int t){
    #pragma unroll
    for (int it = 0; it < 8; ++it){
        int g = it * 2048 + t * 8;
        int r = g >> 7, k = g & 127;
        uint4 v = *((const uint4*)(Wt + r * 128 + k));
        *((uint4*)((char*)Ws + swz(r, k * 2))) = v;
    }
}
__device__ __forceinline__ void mfma_pass(const unsigned short* As, const unsigned short* Ws,
                                          int wr, int wc, int l15, int lh, f32x4 acc[2][4]){
    #pragma unroll
    for (int ks = 0; ks < 4; ++ks){
        const int kc = ks * 32 + lh * 8;
        short8 af[2], bfv[4];
        #pragma unroll
        for (int m = 0; m < 2; m++){
            int r = wr + m * 16 + l15;
            af[m] = *((const short8*)((const char*)As + swz(r, kc * 2)));
        }
        #pragma unroll
        for (int n = 0; n < 4; n++){
            int r = wc + n * 16 + l15;
            bfv[n] = *((const short8*)((const char*)Ws + swz(r, kc * 2)));
        }
        #pragma unroll
        for (int m = 0; m < 2; m++)
            #pragma unroll
            for (int n = 0; n < 4; n++)
                acc[m][n] = __builtin_amdgcn_mfma_f32_16x16x32_bf16(af[m], bfv[n], acc[m][n], 0, 0, 0);
    }
}

// ---- gemm0: hT = (x@W0 + b0) transposed to [j][b*128+col], x is f32 ----
__global__ __launch_bounds__(256) void k_gemm0(const float* __restrict__ x,
                                               const unsigned short* __restrict__ Wt0,
                                               const float* __restrict__ b0,
                                               unsigned short* __restrict__ hT){
    __shared__ unsigned short As[64*128];
    __shared__ unsigned short Ws[128*128];
    const int t = threadIdx.x;
    const int blockRow = blockIdx.x * 64;
    stage_a_f32(x, blockRow, As, t);
    stage_w(Wt0, Ws, t);
    __syncthreads();
    const int lane = t & 63, w = t >> 6;
    const int wr = (w >> 1) * 32, wc = (w & 1) * 64;
    const int l15 = lane & 15, lh = lane >> 4;
    f32x4 acc[2][4];
    #pragma unroll
    for (int m = 0; m < 2; m++) for (int n = 0; n < 4; n++) acc[m][n] = (f32x4)(0.0f);
    mfma_pass(As, Ws, wr, wc, l15, lh, acc);
    #pragma unroll
    for (int m = 0; m < 2; m++){
        #pragma unroll
        for (int rr = 0; rr < 4; rr++){
            int row = blockRow + wr + m * 16 + lh * 4 + rr;
            int b_ = row >> 12, j = row & 4095;
            #pragma unroll
            for (int n = 0; n < 4; n++){
                int col = wc + n * 16 + l15;
                float v = acc[m][n][rr] + b0[col];
                hT[(size_t)j * 1024 + b_ * 128 + col] = f2bf(v);
            }
        }
    }
}

// ---- gemm1: t1bf = x@W1a + agg@W1b + b1 (two K=128 phases) ----
__global__ __launch_bounds__(256) void k_gemm1(const float* __restrict__ x,
                                               const unsigned short* __restrict__ agg,
                                               const unsigned short* __restrict__ Wt1a,
                                               const unsigned short* __restrict__ Wt1b,
                                               const float* __restrict__ b1,
                                               unsigned short* __restrict__ t1bf){
    __shared__ unsigned short As[64*128];
    __shared__ unsigned short Ws[128*128];
    const int t = threadIdx.x;
    const int blockRow = blockIdx.x * 64;
    const int lane = t & 63, w = t >> 6;
    const int wr = (w >> 1) * 32, wc = (w & 1) * 64;
    const int l15 = lane & 15, lh = lane >> 4;
    f32x4 acc[2][4];
    #pragma unroll
    for (int m = 0; m < 2; m++) for (int n = 0; n < 4; n++) acc[m][n] = (f32x4)(0.0f);

    stage_a_f32(x, blockRow, As, t);
    stage_w(Wt1a, Ws, t);
    __syncthreads();
    mfma_pass(As, Ws, wr, wc, l15, lh, acc);
    __syncthreads();
    stage_a_bf16(agg, blockRow, As, t);
    stage_w(Wt1b, Ws, t);
    __syncthreads();
    mfma_pass(As, Ws, wr, wc, l15, lh, acc);

    #pragma unroll
    for (int m = 0; m < 2; m++){
        #pragma unroll
        for (int rr = 0; rr < 4; rr++){
            int row = blockRow + wr + m * 16 + lh * 4 + rr;
            #pragma unroll
            for (int n = 0; n < 4; n++){
                int col = wc + n * 16 + l15;
                float v = acc[m][n][rr] + b1[col];
                t1bf[(size_t)row * 128 + col] = f2bf(v);
            }
        }
    }
}

// ---- gemm23: out = gelu(t1bf@W2 + b2)@Wo + bo + x  (f32 out) ----
__global__ __launch_bounds__(256) void k_gemm23(const unsigned short* __restrict__ t1bf,
                                                const unsigned short* __restrict__ Wt2,
                                                const unsigned short* __restrict__ Wto,
                                                const float* __restrict__ b2,
                                                const float* __restrict__ bo,
                                                const float* __restrict__ x,
                                                float* __restrict__ out){
    __shared__ unsigned short As[64*128];     // reused: t1bf tile, then g tile
    __shared__ unsigned short Ws2[128*128];
    __shared__ unsigned short Wso[128*128];
    const int t = threadIdx.x;
    const int blockRow = blockIdx.x * 64;
    const int lane = t & 63, w = t >> 6;
    const int wr = (w >> 1) * 32, wc = (w & 1) * 64;
    const int l15 = lane & 15, lh = lane >> 4;

    stage_a_bf16(t1bf, blockRow, As, t);
    stage_w(Wt2, Ws2, t);
    stage_w(Wto, Wso, t);
    __syncthreads();

    f32x4 acc[2][4];
    #pragma unroll
    for (int m = 0; m < 2; m++) for (int n = 0; n < 4; n++) acc[m][n] = (f32x4)(0.0f);
    mfma_pass(As, Ws2, wr, wc, l15, lh, acc);
    __syncthreads();

    #pragma unroll
    for (int m = 0; m < 2; m++){
        #pragma unroll
        for (int rr = 0; rr < 4; rr++){
            int rl = wr + m * 16 + lh * 4 + rr;
            #pragma unroll
            for (int n = 0; n < 4; n++){
                int col = wc + n * 16 + l15;
                float v = acc[m][n][rr] + b2[col];
                v = 0.5f * v * (1.0f + erff(v * 0.70710678118f));
                *((unsigned short*)((char*)As + swz(rl, col * 2))) = f2bf(v);
            }
        }
    }
    __syncthreads();

    f32x4 acc2[2][4];
    #pragma unroll
    for (int m = 0; m < 2; m++) for (int n = 0; n < 4; n++) acc2[m][n] = (f32x4)(0.0f);
    mfma_pass(As, Wso, wr, wc, l15, lh, acc2);

    #pragma unroll
    for (int m = 0; m < 2; m++){
        #pragma unroll
        for (int rr = 0; rr < 4; rr++){
            int row = blockRow + wr + m * 16 + lh * 4 + rr;
            #pragma unroll
            for (int n = 0; n < 4; n++){
                int col = wc + n * 16 + l15;
                float v = acc2[m][n][rr] + bo[col] + x[(size_t)row * 128 + col];
                out[(size_t)row * 128 + col] = v;
            }
        }
    }
}

extern "C" void kernel_launch(void* const* d_in, const int* in_sizes, int n_in,
                              void* d_out, int out_size, void* d_ws, size_t ws_size,
                              hipStream_t stream) {
    const float* x  = (const float*)d_in[0];
    const int*   ei = (const int*)d_in[1];
    const float* W0 = (const float*)d_in[2];
    const float* b0 = (const float*)d_in[3];
    const float* W1 = (const float*)d_in[4];
    const float* b1 = (const float*)d_in[5];
    const float* W2 = (const float*)d_in[6];
    const float* b2 = (const float*)d_in[7];
    const float* Wo = (const float*)d_in[8];
    const float* bo = (const float*)d_in[9];
    float* out = (float*)d_out;

    char* ws = (char*)d_ws;
    unsigned int* bits   = (unsigned int*)(ws + 0);                  // 2097152
    int*   cols          = (int*)(ws + 2097152);                     // 8388608
    int*   deg           = (int*)(ws + 10485760);                    // 16384
    unsigned short* hT   = (unsigned short*)(ws + 10502144);         // 8388608
    unsigned short* aggb = (unsigned short*)(ws + 18890752);         // 8388608
    unsigned short* t1bf = (unsigned short*)(ws + 27279360);         // 8388608
    unsigned short* Wt0  = (unsigned short*)(ws + 35667968);
    unsigned short* Wt1a = (unsigned short*)(ws + 35667968 + 32768);
    unsigned short* Wt1b = (unsigned short*)(ws + 35667968 + 65536);
    unsigned short* Wt2  = (unsigned short*)(ws + 35667968 + 98304);
    unsigned short* Wto  = (unsigned short*)(ws + 35667968 + 131072);

    hipMemsetAsync(bits, 0, 2097152, stream);

    k_prep_w<<<320, 256, 0, stream>>>(W0, W1, W2, Wo, Wt0, Wt1a, Wt1b, Wt2, Wto);
    k_scatter<<<EE / 256, 256, 0, stream>>>(ei, bits);
    k_csr<<<NN, 128, 0, stream>>>(bits, cols, deg);

    k_gemm0<<<M_ROWS / 64, 256, 0, stream>>>(x, Wt0, b0, hT);
    k_agg<<<NN, 256, 0, stream>>>(hT, cols, deg, aggb);
    k_gemm1<<<M_ROWS / 64, 256, 0, stream>>>(x, aggb, Wt1a, Wt1b, b1, t1bf);
    k_gemm23<<<M_ROWS / 64, 256, 0, stream>>>(t1bf, Wt2, Wto, b2, bo, x, out);
}

// Round 5
// 92.870 us; speedup vs baseline: 1.2159x; 1.0053x over previous
//
#include <hip/hip_runtime.h>
#include <hip/hip_bf16.h>
#include <math.h>

#define NN 4096
#define BB 8
#define CC 128
#define EE 131072
#define M_ROWS (BB*NN)      // 32768
#define DEG_CAP 512

typedef __attribute__((ext_vector_type(8))) short short8;
typedef __attribute__((ext_vector_type(4))) float f32x4;

__device__ __forceinline__ float bf2f(unsigned int u){
    union { unsigned int i; float f; } v; v.i = u << 16; return v.f;
}
__device__ __forceinline__ unsigned short f2bf(float f){
    union { float f; unsigned int i; } v; v.f = f;
    unsigned int u = v.i;
    unsigned int r = u + 0x7FFFu + ((u >> 16) & 1u);
    return (unsigned short)(r >> 16);
}

// swizzled byte offset for element (row r, k) in a [rows][128] bf16 LDS tile (256B rows)
__device__ __forceinline__ int swz(int r, int k2 /*byte offset in row*/){
    return r * 256 + (k2 ^ ((r & 7) << 4));
}

// ---- zero the 2MB adjacency bitmap (replaces rocclr fillBuffer: 41us -> ~2us) ----
__global__ __launch_bounds__(256) void k_zero(uint4* __restrict__ p){
    int i = blockIdx.x * blockDim.x + threadIdx.x;
    p[i] = (uint4){0u, 0u, 0u, 0u};
}

// ---- transpose+convert weights: Wt[n][k] = W[k][n] as bf16 ----
__global__ __launch_bounds__(256) void k_prep_w(const float* __restrict__ W0, const float* __restrict__ W1,
                                                const float* __restrict__ W2, const float* __restrict__ Wo,
                                                unsigned short* __restrict__ Wt0, unsigned short* __restrict__ Wt1a,
                                                unsigned short* __restrict__ Wt1b, unsigned short* __restrict__ Wt2,
                                                unsigned short* __restrict__ Wto){
    int idx = blockIdx.x * blockDim.x + threadIdx.x;   // 0..81919
    int s = idx >> 14;
    int e = idx & 16383;
    int n = e >> 7, k = e & 127;
    float v; unsigned short* dst;
    switch (s){
        case 0:  v = W0[k*128+n];        dst = Wt0;  break;
        case 1:  v = W1[k*128+n];        dst = Wt1a; break;
        case 2:  v = W1[(128+k)*128+n];  dst = Wt1b; break;
        case 3:  v = W2[k*128+n];        dst = Wt2;  break;
        default: v = Wo[k*128+n];        dst = Wto;  break;
    }
    dst[n*128+k] = f2bf(v);
}

// ---- scatter edges into bitmap adjacency (atomicOr, dedup free) ----
__global__ __launch_bounds__(256) void k_scatter(const int* __restrict__ ei,
                                                 unsigned int* __restrict__ bits){
    int e = blockIdx.x * blockDim.x + threadIdx.x;
    if (e < EE){
        int u = ei[e], v = ei[EE + e];
        atomicOr(&bits[u * 128 + (v >> 5)], 1u << (v & 31));
        atomicOr(&bits[v * 128 + (u >> 5)], 1u << (u & 31));
    }
}

// ---- compact bitmap row -> padded CSR (skip diagonal), 128 thr/block ----
__global__ __launch_bounds__(128) void k_csr(const unsigned int* __restrict__ bits,
                                             int* __restrict__ cols, int* __restrict__ deg){
    __shared__ int sc[128];
    int i = blockIdx.x, t = threadIdx.x;
    unsigned int w = bits[i * 128 + t];
    if (t == (i >> 5)) w &= ~(1u << (i & 31));   // zero diagonal
    int c = __popc(w);
    sc[t] = c; __syncthreads();
    int val = c;
    for (int off = 1; off < 128; off <<= 1){
        int add = (t >= off) ? sc[t - off] : 0;
        __syncthreads();
        val += add; sc[t] = val;
        __syncthreads();
    }
    int total = sc[127];
    int pos = val - c;   // exclusive prefix
    unsigned int ww = w;
    while (ww){
        int b = __ffs(ww) - 1;
        ww &= ww - 1;
        if (pos < DEG_CAP) cols[(size_t)i * DEG_CAP + pos] = t * 32 + b;
        pos++;
    }
    if (t == 0) deg[i] = total < DEG_CAP ? total : DEG_CAP;
}

// ---- sparse aggregation: agg[b,i,:] = sum_{j in N(i)} h[b,j,:] ----
// hT layout: [j][b*128+d] bf16 (2KB/row). Block per i; 128 lanes x 8ch (16B loads);
// two neighbor parity streams across thread halves; cols staged in LDS.
__device__ __forceinline__ void acc8(uint4 u, float* a){
    a[0] += bf2f(u.x & 0xFFFFu); a[1] += bf2f(u.x >> 16);
    a[2] += bf2f(u.y & 0xFFFFu); a[3] += bf2f(u.y >> 16);
    a[4] += bf2f(u.z & 0xFFFFu); a[5] += bf2f(u.z >> 16);
    a[6] += bf2f(u.w & 0xFFFFu); a[7] += bf2f(u.w >> 16);
}

__global__ __launch_bounds__(256) void k_agg(const unsigned short* __restrict__ hT,
                                             const int* __restrict__ cols,
                                             const int* __restrict__ deg,
                                             unsigned short* __restrict__ aggbf){
    __shared__ int scol[DEG_CAP];
    __shared__ float red[128][9];
    const int i = blockIdx.x, t = threadIdx.x;
    const int half = t >> 7, lane = t & 127;
    const int d = deg[i];
    const int* cl = cols + (size_t)i * DEG_CAP;
    for (int q = t; q < d; q += 256) scol[q] = cl[q];
    __syncthreads();

    const unsigned short* hp = hT + lane * 8;
    float a[8];
    #pragma unroll
    for (int c = 0; c < 8; c++) a[c] = 0.f;

    int n = half;
    for (; n + 6 < d; n += 8){
        int j0 = scol[n], j1 = scol[n+2], j2 = scol[n+4], j3 = scol[n+6];
        uint4 u0 = *((const uint4*)(hp + ((size_t)j0 << 10)));
        uint4 u1 = *((const uint4*)(hp + ((size_t)j1 << 10)));
        uint4 u2 = *((const uint4*)(hp + ((size_t)j2 << 10)));
        uint4 u3 = *((const uint4*)(hp + ((size_t)j3 << 10)));
        acc8(u0, a); acc8(u1, a); acc8(u2, a); acc8(u3, a);
    }
    for (; n < d; n += 2){
        uint4 u0 = *((const uint4*)(hp + ((size_t)scol[n] << 10)));
        acc8(u0, a);
    }

    if (half){
        #pragma unroll
        for (int c = 0; c < 8; c++) red[lane][c] = a[c];
    }
    __syncthreads();
    if (!half){
        #pragma unroll
        for (int c = 0; c < 8; c++) a[c] += red[lane][c];
        int b  = lane >> 4;
        int ch = (lane * 8) & 127;
        uint4 o;
        o.x = (unsigned)f2bf(a[0]) | ((unsigned)f2bf(a[1]) << 16);
        o.y = (unsigned)f2bf(a[2]) | ((unsigned)f2bf(a[3]) << 16);
        o.z = (unsigned)f2bf(a[4]) | ((unsigned)f2bf(a[5]) << 16);
        o.w = (unsigned)f2bf(a[6]) | ((unsigned)f2bf(a[7]) << 16);
        *((uint4*)(aggbf + (size_t)b * (NN*128) + (size_t)i * 128 + ch)) = o;
    }
}

// ===== shared GEMM helpers (64-row tiles, 4 waves: 2x2 wave grid of 32x64) =====
__device__ __forceinline__ void stage_a_bf16(const unsigned short* __restrict__ src, int blockRow,
                                             unsigned short* As, int t){
    #pragma unroll
    for (int it = 0; it < 4; ++it){
        int g = it * 2048 + t * 8;
        int r = g >> 7, k = g & 127;
        uint4 v = *((const uint4*)(src + (size_t)(blockRow + r) * 128 + k));
        *((uint4*)((char*)As + swz(r, k * 2))) = v;
    }
}
__device__ __forceinline__ void stage_a_f32(const float* __restrict__ src, int blockRow,
                                            unsigned short* As, int t){
    #pragma unroll
    for (int it = 0; it < 4; ++it){
        int g = it * 2048 + t * 8;
        int r = g >> 7, k = g & 127;
        const float* p = src + (size_t)(blockRow + r) * 128 + k;
        float4 lo = *((const float4*)p);
        float4 hi = *((const float4*)(p + 4));
        ushort4 w0, w1;
        w0.x = f2bf(lo.x); w0.y = f2bf(lo.y); w0.z = f2bf(lo.z); w0.w = f2bf(lo.w);
        w1.x = f2bf(hi.x); w1.y = f2bf(hi.y); w1.z = f2bf(hi.z); w1.w = f2bf(hi.w);
        char* dst = (char*)As + swz(r, k * 2);
        *((ushort4*)dst) = w0;
        *((ushort4*)(dst + 8)) = w1;
    }
}
__device__ __forceinline__ void stage_w(const unsigned short* __restrict__ Wt,
                                        unsigned short* Ws, int t){
    #pragma unroll
    for (int it = 0; it < 8; ++it){
        int g = it * 2048 + t * 8;
        int r = g >> 7, k = g & 127;
        uint4 v = *((const uint4*)(Wt + r * 128 + k));
        *((uint4*)((char*)Ws + swz(r, k * 2))) = v;
    }
}
__device__ __forceinline__ void mfma_pass(const unsigned short* As, const unsigned short* Ws,
                                          int wr, int wc, int l15, int lh, f32x4 acc[2][4]){
    #pragma unroll
    for (int ks = 0; ks < 4; ++ks){
        const int kc = ks * 32 + lh * 8;
        short8 af[2], bfv[4];
        #pragma unroll
        for (int m = 0; m < 2; m++){
            int r = wr + m * 16 + l15;
            af[m] = *((const short8*)((const char*)As + swz(r, kc * 2)));
        }
        #pragma unroll
        for (int n = 0; n < 4; n++){
            int r = wc + n * 16 + l15;
            bfv[n] = *((const short8*)((const char*)Ws + swz(r, kc * 2)));
        }
        #pragma unroll
        for (int m = 0; m < 2; m++)
            #pragma unroll
            for (int n = 0; n < 4; n++)
                acc[m][n] = __builtin_amdgcn_mfma_f32_16x16x32_bf16(af[m], bfv[n], acc[m][n], 0, 0, 0);
    }
}

// ---- gemm0: hT = (x@W0 + b0) transposed to [j][b*128+col], x is f32 ----
__global__ __launch_bounds__(256) void k_gemm0(const float* __restrict__ x,
                                               const unsigned short* __restrict__ Wt0,
                                               const float* __restrict__ b0,
                                               unsigned short* __restrict__ hT){
    __shared__ unsigned short As[64*128];
    __shared__ unsigned short Ws[128*128];
    const int t = threadIdx.x;
    const int blockRow = blockIdx.x * 64;
    stage_a_f32(x, blockRow, As, t);
    stage_w(Wt0, Ws, t);
    __syncthreads();
    const int lane = t & 63, w = t >> 6;
    const int wr = (w >> 1) * 32, wc = (w & 1) * 64;
    const int l15 = lane & 15, lh = lane >> 4;
    f32x4 acc[2][4];
    #pragma unroll
    for (int m = 0; m < 2; m++) for (int n = 0; n < 4; n++) acc[m][n] = (f32x4)(0.0f);
    mfma_pass(As, Ws, wr, wc, l15, lh, acc);
    #pragma unroll
    for (int m = 0; m < 2; m++){
        #pragma unroll
        for (int rr = 0; rr < 4; rr++){
            int row = blockRow + wr + m * 16 + lh * 4 + rr;
            int b_ = row >> 12, j = row & 4095;
            #pragma unroll
            for (int n = 0; n < 4; n++){
                int col = wc + n * 16 + l15;
                float v = acc[m][n][rr] + b0[col];
                hT[(size_t)j * 1024 + b_ * 128 + col] = f2bf(v);
            }
        }
    }
}

// ---- gemm1: t1bf = x@W1a + agg@W1b + b1 (two K=128 phases) ----
__global__ __launch_bounds__(256) void k_gemm1(const float* __restrict__ x,
                                               const unsigned short* __restrict__ agg,
                                               const unsigned short* __restrict__ Wt1a,
                                               const unsigned short* __restrict__ Wt1b,
                                               const float* __restrict__ b1,
                                               unsigned short* __restrict__ t1bf){
    __shared__ unsigned short As[64*128];
    __shared__ unsigned short Ws[128*128];
    const int t = threadIdx.x;
    const int blockRow = blockIdx.x * 64;
    const int lane = t & 63, w = t >> 6;
    const int wr = (w >> 1) * 32, wc = (w & 1) * 64;
    const int l15 = lane & 15, lh = lane >> 4;
    f32x4 acc[2][4];
    #pragma unroll
    for (int m = 0; m < 2; m++) for (int n = 0; n < 4; n++) acc[m][n] = (f32x4)(0.0f);

    stage_a_f32(x, blockRow, As, t);
    stage_w(Wt1a, Ws, t);
    __syncthreads();
    mfma_pass(As, Ws, wr, wc, l15, lh, acc);
    __syncthreads();
    stage_a_bf16(agg, blockRow, As, t);
    stage_w(Wt1b, Ws, t);
    __syncthreads();
    mfma_pass(As, Ws, wr, wc, l15, lh, acc);

    #pragma unroll
    for (int m = 0; m < 2; m++){
        #pragma unroll
        for (int rr = 0; rr < 4; rr++){
            int row = blockRow + wr + m * 16 + lh * 4 + rr;
            #pragma unroll
            for (int n = 0; n < 4; n++){
                int col = wc + n * 16 + l15;
                float v = acc[m][n][rr] + b1[col];
                t1bf[(size_t)row * 128 + col] = f2bf(v);
            }
        }
    }
}

// ---- gemm23: out = gelu(t1bf@W2 + b2)@Wo + bo + x  (f32 out) ----
__global__ __launch_bounds__(256) void k_gemm23(const unsigned short* __restrict__ t1bf,
                                                const unsigned short* __restrict__ Wt2,
                                                const unsigned short* __restrict__ Wto,
                                                const float* __restrict__ b2,
                                                const float* __restrict__ bo,
                                                const float* __restrict__ x,
                                                float* __restrict__ out){
    __shared__ unsigned short As[64*128];     // reused: t1bf tile, then g tile
    __shared__ unsigned short Ws2[128*128];
    __shared__ unsigned short Wso[128*128];
    const int t = threadIdx.x;
    const int blockRow = blockIdx.x * 64;
    const int lane = t & 63, w = t >> 6;
    const int wr = (w >> 1) * 32, wc = (w & 1) * 64;
    const int l15 = lane & 15, lh = lane >> 4;

    stage_a_bf16(t1bf, blockRow, As, t);
    stage_w(Wt2, Ws2, t);
    stage_w(Wto, Wso, t);
    __syncthreads();

    f32x4 acc[2][4];
    #pragma unroll
    for (int m = 0; m < 2; m++) for (int n = 0; n < 4; n++) acc[m][n] = (f32x4)(0.0f);
    mfma_pass(As, Ws2, wr, wc, l15, lh, acc);
    __syncthreads();

    #pragma unroll
    for (int m = 0; m < 2; m++){
        #pragma unroll
        for (int rr = 0; rr < 4; rr++){
            int rl = wr + m * 16 + lh * 4 + rr;
            #pragma unroll
            for (int n = 0; n < 4; n++){
                int col = wc + n * 16 + l15;
                float v = acc[m][n][rr] + b2[col];
                v = 0.5f * v * (1.0f + erff(v * 0.70710678118f));
                *((unsigned short*)((char*)As + swz(rl, col * 2))) = f2bf(v);
            }
        }
    }
    __syncthreads();

    f32x4 acc2[2][4];
    #pragma unroll
    for (int m = 0; m < 2; m++) for (int n = 0; n < 4; n++) acc2[m][n] = (f32x4)(0.0f);
    mfma_pass(As, Wso, wr, wc, l15, lh, acc2);

    #pragma unroll
    for (int m = 0; m < 2; m++){
        #pragma unroll
        for (int rr = 0; rr < 4; rr++){
            int row = blockRow + wr + m * 16 + lh * 4 + rr;
            #pragma unroll
            for (int n = 0; n < 4; n++){
                int col = wc + n * 16 + l15;
                float v = acc2[m][n][rr] + bo[col] + x[(size_t)row * 128 + col];
                out[(size_t)row * 128 + col] = v;
            }
        }
    }
}

extern "C" void kernel_launch(void* const* d_in, const int* in_sizes, int n_in,
                              void* d_out, int out_size, void* d_ws, size_t ws_size,
                              hipStream_t stream) {
    const float* x  = (const float*)d_in[0];
    const int*   ei = (const int*)d_in[1];
    const float* W0 = (const float*)d_in[2];
    const float* b0 = (const float*)d_in[3];
    const float* W1 = (const float*)d_in[4];
    const float* b1 = (const float*)d_in[5];
    const float* W2 = (const float*)d_in[6];
    const float* b2 = (const float*)d_in[7];
    const float* Wo = (const float*)d_in[8];
    const float* bo = (const float*)d_in[9];
    float* out = (float*)d_out;

    char* ws = (char*)d_ws;
    unsigned int* bits   = (unsigned int*)(ws + 0);                  // 2097152
    int*   cols          = (int*)(ws + 2097152);                     // 8388608
    int*   deg           = (int*)(ws + 10485760);                    // 16384
    unsigned short* hT   = (unsigned short*)(ws + 10502144);         // 8388608
    unsigned short* aggb = (unsigned short*)(ws + 18890752);         // 8388608
    unsigned short* t1bf = (unsigned short*)(ws + 27279360);         // 8388608
    unsigned short* Wt0  = (unsigned short*)(ws + 35667968);
    unsigned short* Wt1a = (unsigned short*)(ws + 35667968 + 32768);
    unsigned short* Wt1b = (unsigned short*)(ws + 35667968 + 65536);
    unsigned short* Wt2  = (unsigned short*)(ws + 35667968 + 98304);
    unsigned short* Wto  = (unsigned short*)(ws + 35667968 + 131072);

    // zero 2MB bitmap: 2097152 / (256 thr * 16 B) = 512 blocks
    k_zero<<<512, 256, 0, stream>>>((uint4*)bits);
    k_prep_w<<<320, 256, 0, stream>>>(W0, W1, W2, Wo, Wt0, Wt1a, Wt1b, Wt2, Wto);
    k_scatter<<<EE / 256, 256, 0, stream>>>(ei, bits);
    k_csr<<<NN, 128, 0, stream>>>(bits, cols, deg);

    k_gemm0<<<M_ROWS / 64, 256, 0, stream>>>(x, Wt0, b0, hT);
    k_agg<<<NN, 256, 0, stream>>>(hT, cols, deg, aggb);
    k_gemm1<<<M_ROWS / 64, 256, 0, stream>>>(x, aggb, Wt1a, Wt1b, b1, t1bf);
    k_gemm23<<<M_ROWS / 64, 256, 0, stream>>>(t1bf, Wt2, Wto, b2, bo, x, out);
}

// Round 6
// 80.676 us; speedup vs baseline: 1.3997x; 1.1512x over previous
//
#include <hip/hip_runtime.h>
#include <hip/hip_bf16.h>
#include <math.h>

#define NN 4096
#define BB 8
#define CC 128
#define EE 131072
#define M_ROWS (BB*NN)      // 32768
#define DEG_CAP 512

typedef __attribute__((ext_vector_type(8))) short short8;
typedef __attribute__((ext_vector_type(4))) float f32x4;

__device__ __forceinline__ float bf2f(unsigned int u){
    union { unsigned int i; float f; } v; v.i = u << 16; return v.f;
}
__device__ __forceinline__ unsigned short f2bf(float f){
    union { float f; unsigned int i; } v; v.f = f;
    unsigned int u = v.i;
    unsigned int r = u + 0x7FFFu + ((u >> 16) & 1u);
    return (unsigned short)(r >> 16);
}

// swizzled byte offset for element (row r, k) in a [rows][128] bf16 LDS tile (256B rows)
__device__ __forceinline__ int swz(int r, int k2 /*byte offset in row*/){
    return r * 256 + (k2 ^ ((r & 7) << 4));
}

// ---- fused: zero 2MB bitmap (blocks 0..511) + weight transpose (blocks 512..831) ----
__global__ __launch_bounds__(256) void k_init(uint4* __restrict__ bits4,
                                              const float* __restrict__ W0, const float* __restrict__ W1,
                                              const float* __restrict__ W2, const float* __restrict__ Wo,
                                              unsigned short* __restrict__ Wt0, unsigned short* __restrict__ Wt1a,
                                              unsigned short* __restrict__ Wt1b, unsigned short* __restrict__ Wt2,
                                              unsigned short* __restrict__ Wto){
    int bid = blockIdx.x, t = threadIdx.x;
    if (bid < 512){
        bits4[bid * 256 + t] = (uint4){0u, 0u, 0u, 0u};
        return;
    }
    int idx = (bid - 512) * 256 + t;   // 0..81919
    int s = idx >> 14;
    int e = idx & 16383;
    int n = e >> 7, k = e & 127;
    float v; unsigned short* dst;
    switch (s){
        case 0:  v = W0[k*128+n];        dst = Wt0;  break;
        case 1:  v = W1[k*128+n];        dst = Wt1a; break;
        case 2:  v = W1[(128+k)*128+n];  dst = Wt1b; break;
        case 3:  v = W2[k*128+n];        dst = Wt2;  break;
        default: v = Wo[k*128+n];        dst = Wto;  break;
    }
    dst[n*128+k] = f2bf(v);
}

// ---- scatter edges into bitmap adjacency (atomicOr, dedup free) ----
__global__ __launch_bounds__(256) void k_scatter(const int* __restrict__ ei,
                                                 unsigned int* __restrict__ bits){
    int e = blockIdx.x * blockDim.x + threadIdx.x;
    if (e < EE){
        int u = ei[e], v = ei[EE + e];
        atomicOr(&bits[u * 128 + (v >> 5)], 1u << (v & 31));
        atomicOr(&bits[v * 128 + (u >> 5)], 1u << (u & 31));
    }
}

// ---- compact bitmap row -> padded CSR (skip diagonal), 128 thr/block ----
__global__ __launch_bounds__(128) void k_csr(const unsigned int* __restrict__ bits,
                                             int* __restrict__ cols, int* __restrict__ deg){
    __shared__ int sc[128];
    int i = blockIdx.x, t = threadIdx.x;
    unsigned int w = bits[i * 128 + t];
    if (t == (i >> 5)) w &= ~(1u << (i & 31));   // zero diagonal
    int c = __popc(w);
    sc[t] = c; __syncthreads();
    int val = c;
    for (int off = 1; off < 128; off <<= 1){
        int add = (t >= off) ? sc[t - off] : 0;
        __syncthreads();
        val += add; sc[t] = val;
        __syncthreads();
    }
    int total = sc[127];
    int pos = val - c;   // exclusive prefix
    unsigned int ww = w;
    while (ww){
        int b = __ffs(ww) - 1;
        ww &= ww - 1;
        if (pos < DEG_CAP) cols[(size_t)i * DEG_CAP + pos] = t * 32 + b;
        pos++;
    }
    if (t == 0) deg[i] = total < DEG_CAP ? total : DEG_CAP;
}

// ---- sparse aggregation, per-batch L2-resident: agg[b,i,:] = sum_j h[b,j,:] ----
// h natural layout [b][j][128] bf16 -> per-batch table is 1MB (L2-resident/XCD).
// One wave per (b,i): neighbor row = 256B = 64 lanes x 4B (uint = 2 channels).
__global__ __launch_bounds__(256) void k_agg(const unsigned short* __restrict__ h,
                                             const int* __restrict__ cols,
                                             const int* __restrict__ deg,
                                             unsigned short* __restrict__ agg){
    __shared__ int scol[4][DEG_CAP];
    const int t = threadIdx.x;
    const int w = t >> 6, lane = t & 63;
    const int b = blockIdx.x >> 10;               // batch-major: blocks of same batch adjacent
    const int i = ((blockIdx.x & 1023) << 2) + w; // node
    const int d = deg[i];
    const int* cl = cols + (size_t)i * DEG_CAP;
    for (int q = lane; q < d; q += 64) scol[w][q] = cl[q];
    // same-wave LDS RAW: ordered by lgkmcnt, no block barrier needed

    const unsigned short* hb = h + (size_t)b * (NN*128) + lane * 2;
    float a0 = 0.f, a1 = 0.f;
    int n = 0;
    for (; n + 3 < d; n += 4){
        int j0 = scol[w][n], j1 = scol[w][n+1], j2 = scol[w][n+2], j3 = scol[w][n+3];
        unsigned int u0 = *((const unsigned int*)(hb + ((size_t)j0 << 7)));
        unsigned int u1 = *((const unsigned int*)(hb + ((size_t)j1 << 7)));
        unsigned int u2 = *((const unsigned int*)(hb + ((size_t)j2 << 7)));
        unsigned int u3 = *((const unsigned int*)(hb + ((size_t)j3 << 7)));
        a0 += bf2f(u0 & 0xFFFFu) + bf2f(u1 & 0xFFFFu) + bf2f(u2 & 0xFFFFu) + bf2f(u3 & 0xFFFFu);
        a1 += bf2f(u0 >> 16)     + bf2f(u1 >> 16)     + bf2f(u2 >> 16)     + bf2f(u3 >> 16);
    }
    for (; n < d; ++n){
        unsigned int u0 = *((const unsigned int*)(hb + ((size_t)scol[w][n] << 7)));
        a0 += bf2f(u0 & 0xFFFFu);
        a1 += bf2f(u0 >> 16);
    }
    unsigned int o = (unsigned)f2bf(a0) | ((unsigned)f2bf(a1) << 16);
    *((unsigned int*)(agg + (size_t)b * (NN*128) + ((size_t)i << 7) + lane * 2)) = o;
}

// ===== shared GEMM helpers (64-row tiles, 4 waves: 2x2 wave grid of 32x64) =====
__device__ __forceinline__ void stage_a_bf16(const unsigned short* __restrict__ src, int blockRow,
                                             unsigned short* As, int t){
    #pragma unroll
    for (int it = 0; it < 4; ++it){
        int g = it * 2048 + t * 8;
        int r = g >> 7, k = g & 127;
        uint4 v = *((const uint4*)(src + (size_t)(blockRow + r) * 128 + k));
        *((uint4*)((char*)As + swz(r, k * 2))) = v;
    }
}
__device__ __forceinline__ void stage_a_f32(const float* __restrict__ src, int blockRow,
                                            unsigned short* As, int t){
    #pragma unroll
    for (int it = 0; it < 4; ++it){
        int g = it * 2048 + t * 8;
        int r = g >> 7, k = g & 127;
        const float* p = src + (size_t)(blockRow + r) * 128 + k;
        float4 lo = *((const float4*)p);
        float4 hi = *((const float4*)(p + 4));
        ushort4 w0, w1;
        w0.x = f2bf(lo.x); w0.y = f2bf(lo.y); w0.z = f2bf(lo.z); w0.w = f2bf(lo.w);
        w1.x = f2bf(hi.x); w1.y = f2bf(hi.y); w1.z = f2bf(hi.z); w1.w = f2bf(hi.w);
        char* dst = (char*)As + swz(r, k * 2);
        *((ushort4*)dst) = w0;
        *((ushort4*)(dst + 8)) = w1;
    }
}
__device__ __forceinline__ void stage_w(const unsigned short* __restrict__ Wt,
                                        unsigned short* Ws, int t){
    #pragma unroll
    for (int it = 0; it < 8; ++it){
        int g = it * 2048 + t * 8;
        int r = g >> 7, k = g & 127;
        uint4 v = *((const uint4*)(Wt + r * 128 + k));
        *((uint4*)((char*)Ws + swz(r, k * 2))) = v;
    }
}
__device__ __forceinline__ void mfma_pass(const unsigned short* As, const unsigned short* Ws,
                                          int wr, int wc, int l15, int lh, f32x4 acc[2][4]){
    #pragma unroll
    for (int ks = 0; ks < 4; ++ks){
        const int kc = ks * 32 + lh * 8;
        short8 af[2], bfv[4];
        #pragma unroll
        for (int m = 0; m < 2; m++){
            int r = wr + m * 16 + l15;
            af[m] = *((const short8*)((const char*)As + swz(r, kc * 2)));
        }
        #pragma unroll
        for (int n = 0; n < 4; n++){
            int r = wc + n * 16 + l15;
            bfv[n] = *((const short8*)((const char*)Ws + swz(r, kc * 2)));
        }
        #pragma unroll
        for (int m = 0; m < 2; m++)
            #pragma unroll
            for (int n = 0; n < 4; n++)
                acc[m][n] = __builtin_amdgcn_mfma_f32_16x16x32_bf16(af[m], bfv[n], acc[m][n], 0, 0, 0);
    }
}

// ---- gemm0: h = x@W0 + b0 (natural layout [b][j][128] bf16) ----
__global__ __launch_bounds__(256) void k_gemm0(const float* __restrict__ x,
                                               const unsigned short* __restrict__ Wt0,
                                               const float* __restrict__ b0,
                                               unsigned short* __restrict__ h){
    __shared__ unsigned short As[64*128];
    __shared__ unsigned short Ws[128*128];
    const int t = threadIdx.x;
    const int blockRow = blockIdx.x * 64;
    stage_a_f32(x, blockRow, As, t);
    stage_w(Wt0, Ws, t);
    __syncthreads();
    const int lane = t & 63, w = t >> 6;
    const int wr = (w >> 1) * 32, wc = (w & 1) * 64;
    const int l15 = lane & 15, lh = lane >> 4;
    f32x4 acc[2][4];
    #pragma unroll
    for (int m = 0; m < 2; m++) for (int n = 0; n < 4; n++) acc[m][n] = (f32x4)(0.0f);
    mfma_pass(As, Ws, wr, wc, l15, lh, acc);
    #pragma unroll
    for (int m = 0; m < 2; m++){
        #pragma unroll
        for (int rr = 0; rr < 4; rr++){
            int row = blockRow + wr + m * 16 + lh * 4 + rr;
            #pragma unroll
            for (int n = 0; n < 4; n++){
                int col = wc + n * 16 + l15;
                float v = acc[m][n][rr] + b0[col];
                h[(size_t)row * 128 + col] = f2bf(v);
            }
        }
    }
}

// ---- gemm1: t1bf = x@W1a + agg@W1b + b1 (two K=128 phases) ----
__global__ __launch_bounds__(256) void k_gemm1(const float* __restrict__ x,
                                               const unsigned short* __restrict__ agg,
                                               const unsigned short* __restrict__ Wt1a,
                                               const unsigned short* __restrict__ Wt1b,
                                               const float* __restrict__ b1,
                                               unsigned short* __restrict__ t1bf){
    __shared__ unsigned short As[64*128];
    __shared__ unsigned short Ws[128*128];
    const int t = threadIdx.x;
    const int blockRow = blockIdx.x * 64;
    const int lane = t & 63, w = t >> 6;
    const int wr = (w >> 1) * 32, wc = (w & 1) * 64;
    const int l15 = lane & 15, lh = lane >> 4;
    f32x4 acc[2][4];
    #pragma unroll
    for (int m = 0; m < 2; m++) for (int n = 0; n < 4; n++) acc[m][n] = (f32x4)(0.0f);

    stage_a_f32(x, blockRow, As, t);
    stage_w(Wt1a, Ws, t);
    __syncthreads();
    mfma_pass(As, Ws, wr, wc, l15, lh, acc);
    __syncthreads();
    stage_a_bf16(agg, blockRow, As, t);
    stage_w(Wt1b, Ws, t);
    __syncthreads();
    mfma_pass(As, Ws, wr, wc, l15, lh, acc);

    #pragma unroll
    for (int m = 0; m < 2; m++){
        #pragma unroll
        for (int rr = 0; rr < 4; rr++){
            int row = blockRow + wr + m * 16 + lh * 4 + rr;
            #pragma unroll
            for (int n = 0; n < 4; n++){
                int col = wc + n * 16 + l15;
                float v = acc[m][n][rr] + b1[col];
                t1bf[(size_t)row * 128 + col] = f2bf(v);
            }
        }
    }
}

// ---- gemm23: out = gelu(t1bf@W2 + b2)@Wo + bo + x  (f32 out) ----
__global__ __launch_bounds__(256) void k_gemm23(const unsigned short* __restrict__ t1bf,
                                                const unsigned short* __restrict__ Wt2,
                                                const unsigned short* __restrict__ Wto,
                                                const float* __restrict__ b2,
                                                const float* __restrict__ bo,
                                                const float* __restrict__ x,
                                                float* __restrict__ out){
    __shared__ unsigned short As[64*128];     // reused: t1bf tile, then g tile
    __shared__ unsigned short Ws2[128*128];
    __shared__ unsigned short Wso[128*128];
    const int t = threadIdx.x;
    const int blockRow = blockIdx.x * 64;
    const int lane = t & 63, w = t >> 6;
    const int wr = (w >> 1) * 32, wc = (w & 1) * 64;
    const int l15 = lane & 15, lh = lane >> 4;

    stage_a_bf16(t1bf, blockRow, As, t);
    stage_w(Wt2, Ws2, t);
    stage_w(Wto, Wso, t);
    __syncthreads();

    f32x4 acc[2][4];
    #pragma unroll
    for (int m = 0; m < 2; m++) for (int n = 0; n < 4; n++) acc[m][n] = (f32x4)(0.0f);
    mfma_pass(As, Ws2, wr, wc, l15, lh, acc);
    __syncthreads();

    #pragma unroll
    for (int m = 0; m < 2; m++){
        #pragma unroll
        for (int rr = 0; rr < 4; rr++){
            int rl = wr + m * 16 + lh * 4 + rr;
            #pragma unroll
            for (int n = 0; n < 4; n++){
                int col = wc + n * 16 + l15;
                float v = acc[m][n][rr] + b2[col];
                v = 0.5f * v * (1.0f + erff(v * 0.70710678118f));
                *((unsigned short*)((char*)As + swz(rl, col * 2))) = f2bf(v);
            }
        }
    }
    __syncthreads();

    f32x4 acc2[2][4];
    #pragma unroll
    for (int m = 0; m < 2; m++) for (int n = 0; n < 4; n++) acc2[m][n] = (f32x4)(0.0f);
    mfma_pass(As, Wso, wr, wc, l15, lh, acc2);

    #pragma unroll
    for (int m = 0; m < 2; m++){
        #pragma unroll
        for (int rr = 0; rr < 4; rr++){
            int row = blockRow + wr + m * 16 + lh * 4 + rr;
            #pragma unroll
            for (int n = 0; n < 4; n++){
                int col = wc + n * 16 + l15;
                float v = acc2[m][n][rr] + bo[col] + x[(size_t)row * 128 + col];
                out[(size_t)row * 128 + col] = v;
            }
        }
    }
}

extern "C" void kernel_launch(void* const* d_in, const int* in_sizes, int n_in,
                              void* d_out, int out_size, void* d_ws, size_t ws_size,
                              hipStream_t stream) {
    const float* x  = (const float*)d_in[0];
    const int*   ei = (const int*)d_in[1];
    const float* W0 = (const float*)d_in[2];
    const float* b0 = (const float*)d_in[3];
    const float* W1 = (const float*)d_in[4];
    const float* b1 = (const float*)d_in[5];
    const float* W2 = (const float*)d_in[6];
    const float* b2 = (const float*)d_in[7];
    const float* Wo = (const float*)d_in[8];
    const float* bo = (const float*)d_in[9];
    float* out = (float*)d_out;

    char* ws = (char*)d_ws;
    unsigned int* bits   = (unsigned int*)(ws + 0);                  // 2097152
    int*   cols          = (int*)(ws + 2097152);                     // 8388608
    int*   deg           = (int*)(ws + 10485760);                    // 16384
    unsigned short* h    = (unsigned short*)(ws + 10502144);         // 8388608
    unsigned short* aggb = (unsigned short*)(ws + 18890752);         // 8388608
    unsigned short* t1bf = (unsigned short*)(ws + 27279360);         // 8388608
    unsigned short* Wt0  = (unsigned short*)(ws + 35667968);
    unsigned short* Wt1a = (unsigned short*)(ws + 35667968 + 32768);
    unsigned short* Wt1b = (unsigned short*)(ws + 35667968 + 65536);
    unsigned short* Wt2  = (unsigned short*)(ws + 35667968 + 98304);
    unsigned short* Wto  = (unsigned short*)(ws + 35667968 + 131072);

    k_init<<<832, 256, 0, stream>>>((uint4*)bits, W0, W1, W2, Wo, Wt0, Wt1a, Wt1b, Wt2, Wto);
    k_scatter<<<EE / 256, 256, 0, stream>>>(ei, bits);
    k_csr<<<NN, 128, 0, stream>>>(bits, cols, deg);

    k_gemm0<<<M_ROWS / 64, 256, 0, stream>>>(x, Wt0, b0, h);
    k_agg<<<BB * (NN / 4), 256, 0, stream>>>(h, cols, deg, aggb);
    k_gemm1<<<M_ROWS / 64, 256, 0, stream>>>(x, aggb, Wt1a, Wt1b, b1, t1bf);
    k_gemm23<<<M_ROWS / 64, 256, 0, stream>>>(t1bf, Wt2, Wto, b2, bo, x, out);
}

// Round 7
// 79.793 us; speedup vs baseline: 1.4152x; 1.0111x over previous
//
#include <hip/hip_runtime.h>
#include <hip/hip_bf16.h>
#include <math.h>

#define NN 4096
#define BB 8
#define CC 128
#define EE 131072
#define M_ROWS (BB*NN)      // 32768
#define DEG_CAP 512

typedef __attribute__((ext_vector_type(8))) short short8;
typedef __attribute__((ext_vector_type(4))) float f32x4;

__device__ __forceinline__ float bf2f(unsigned int u){
    union { unsigned int i; float f; } v; v.i = u << 16; return v.f;
}
__device__ __forceinline__ unsigned short f2bf(float f){
    union { float f; unsigned int i; } v; v.f = f;
    unsigned int u = v.i;
    unsigned int r = u + 0x7FFFu + ((u >> 16) & 1u);
    return (unsigned short)(r >> 16);
}

// swizzled byte offset for element (row r, k) in a [rows][128] bf16 LDS tile (256B rows)
__device__ __forceinline__ int swz(int r, int k2 /*byte offset in row*/){
    return r * 256 + (k2 ^ ((r & 7) << 4));
}

// ---- fused: zero 2MB bitmap (blocks 0..511) + weight transpose (blocks 512..831) ----
__global__ __launch_bounds__(256) void k_init(uint4* __restrict__ bits4,
                                              const float* __restrict__ W0, const float* __restrict__ W1,
                                              const float* __restrict__ W2, const float* __restrict__ Wo,
                                              unsigned short* __restrict__ Wt0, unsigned short* __restrict__ Wt1a,
                                              unsigned short* __restrict__ Wt1b, unsigned short* __restrict__ Wt2,
                                              unsigned short* __restrict__ Wto){
    int bid = blockIdx.x, t = threadIdx.x;
    if (bid < 512){
        bits4[bid * 256 + t] = (uint4){0u, 0u, 0u, 0u};
        return;
    }
    int idx = (bid - 512) * 256 + t;   // 0..81919
    int s = idx >> 14;
    int e = idx & 16383;
    int n = e >> 7, k = e & 127;
    float v; unsigned short* dst;
    switch (s){
        case 0:  v = W0[k*128+n];        dst = Wt0;  break;
        case 1:  v = W1[k*128+n];        dst = Wt1a; break;
        case 2:  v = W1[(128+k)*128+n];  dst = Wt1b; break;
        case 3:  v = W2[k*128+n];        dst = Wt2;  break;
        default: v = Wo[k*128+n];        dst = Wto;  break;
    }
    dst[n*128+k] = f2bf(v);
}

// ---- scatter edges into bitmap adjacency (atomicOr, dedup free) ----
__global__ __launch_bounds__(256) void k_scatter(const int* __restrict__ ei,
                                                 unsigned int* __restrict__ bits){
    int e = blockIdx.x * blockDim.x + threadIdx.x;
    if (e < EE){
        int u = ei[e], v = ei[EE + e];
        atomicOr(&bits[u * 128 + (v >> 5)], 1u << (v & 31));
        atomicOr(&bits[v * 128 + (u >> 5)], 1u << (u & 31));
    }
}

// ---- compact bitmap row -> padded CSR (skip diagonal), 128 thr/block ----
__global__ __launch_bounds__(128) void k_csr(const unsigned int* __restrict__ bits,
                                             int* __restrict__ cols, int* __restrict__ deg){
    __shared__ int sc[128];
    int i = blockIdx.x, t = threadIdx.x;
    unsigned int w = bits[i * 128 + t];
    if (t == (i >> 5)) w &= ~(1u << (i & 31));   // zero diagonal
    int c = __popc(w);
    sc[t] = c; __syncthreads();
    int val = c;
    for (int off = 1; off < 128; off <<= 1){
        int add = (t >= off) ? sc[t - off] : 0;
        __syncthreads();
        val += add; sc[t] = val;
        __syncthreads();
    }
    int total = sc[127];
    int pos = val - c;   // exclusive prefix
    unsigned int ww = w;
    while (ww){
        int b = __ffs(ww) - 1;
        ww &= ww - 1;
        if (pos < DEG_CAP) cols[(size_t)i * DEG_CAP + pos] = t * 32 + b;
        pos++;
    }
    if (t == 0) deg[i] = total < DEG_CAP ? total : DEG_CAP;
}

// ---- sparse aggregation, per-batch L2-resident, 4 rows per wave-load ----
// h natural layout [b][j][128] bf16 (256B rows, 1MB per-batch table).
// One wave per (b,i). Lane = (sub=lane>>4, li=lane&15): sub selects neighbor
// stream (4 rows in flight per load instr), li covers 8 channels via uint4.
__device__ __forceinline__ void acc8u(uint4 u, float* a){
    a[0] += bf2f(u.x & 0xFFFFu); a[1] += bf2f(u.x >> 16);
    a[2] += bf2f(u.y & 0xFFFFu); a[3] += bf2f(u.y >> 16);
    a[4] += bf2f(u.z & 0xFFFFu); a[5] += bf2f(u.z >> 16);
    a[6] += bf2f(u.w & 0xFFFFu); a[7] += bf2f(u.w >> 16);
}

__global__ __launch_bounds__(256) void k_agg(const unsigned short* __restrict__ h,
                                             const int* __restrict__ cols,
                                             const int* __restrict__ deg,
                                             unsigned short* __restrict__ agg){
    __shared__ int scol[4][DEG_CAP];
    const int t = threadIdx.x;
    const int w = t >> 6, lane = t & 63;
    const int sub = lane >> 4, li = lane & 15;
    const int b = blockIdx.x >> 10;               // batch-major
    const int i = ((blockIdx.x & 1023) << 2) + w; // node
    const int d = deg[i];
    const int* cl = cols + (size_t)i * DEG_CAP;
    for (int q = lane; q < d; q += 64) scol[w][q] = cl[q];
    // same-wave LDS RAW: DS pipe processes ops in order per wave

    const unsigned short* hb = h + (size_t)b * (NN*128) + li * 8;
    float a[8];
    #pragma unroll
    for (int c = 0; c < 8; c++) a[c] = 0.f;

    int n = sub;
    for (; n + 4 < d; n += 8){
        int j0 = scol[w][n], j1 = scol[w][n+4];
        uint4 u0 = *((const uint4*)(hb + ((size_t)j0 << 7)));
        uint4 u1 = *((const uint4*)(hb + ((size_t)j1 << 7)));
        acc8u(u0, a); acc8u(u1, a);
    }
    if (n < d){
        uint4 u0 = *((const uint4*)(hb + ((size_t)scol[w][n] << 7)));
        acc8u(u0, a);
    }

    // reduce across the 4 sub-groups (lanes differing in bits 4,5)
    #pragma unroll
    for (int c = 0; c < 8; c++){
        a[c] += __shfl_xor(a[c], 16);
        a[c] += __shfl_xor(a[c], 32);
    }
    if (sub == 0){
        uint4 o;
        o.x = (unsigned)f2bf(a[0]) | ((unsigned)f2bf(a[1]) << 16);
        o.y = (unsigned)f2bf(a[2]) | ((unsigned)f2bf(a[3]) << 16);
        o.z = (unsigned)f2bf(a[4]) | ((unsigned)f2bf(a[5]) << 16);
        o.w = (unsigned)f2bf(a[6]) | ((unsigned)f2bf(a[7]) << 16);
        *((uint4*)(agg + (size_t)b * (NN*128) + ((size_t)i << 7) + li * 8)) = o;
    }
}

// ===== shared GEMM helpers (64-row tiles, 4 waves: 2x2 wave grid of 32x64) =====
__device__ __forceinline__ void stage_a_bf16(const unsigned short* __restrict__ src, int blockRow,
                                             unsigned short* As, int t){
    #pragma unroll
    for (int it = 0; it < 4; ++it){
        int g = it * 2048 + t * 8;
        int r = g >> 7, k = g & 127;
        uint4 v = *((const uint4*)(src + (size_t)(blockRow + r) * 128 + k));
        *((uint4*)((char*)As + swz(r, k * 2))) = v;
    }
}
__device__ __forceinline__ void stage_a_f32(const float* __restrict__ src, int blockRow,
                                            unsigned short* As, int t){
    #pragma unroll
    for (int it = 0; it < 4; ++it){
        int g = it * 2048 + t * 8;
        int r = g >> 7, k = g & 127;
        const float* p = src + (size_t)(blockRow + r) * 128 + k;
        float4 lo = *((const float4*)p);
        float4 hi = *((const float4*)(p + 4));
        ushort4 w0, w1;
        w0.x = f2bf(lo.x); w0.y = f2bf(lo.y); w0.z = f2bf(lo.z); w0.w = f2bf(lo.w);
        w1.x = f2bf(hi.x); w1.y = f2bf(hi.y); w1.z = f2bf(hi.z); w1.w = f2bf(hi.w);
        char* dst = (char*)As + swz(r, k * 2);
        *((ushort4*)dst) = w0;
        *((ushort4*)(dst + 8)) = w1;
    }
}
__device__ __forceinline__ void stage_w(const unsigned short* __restrict__ Wt,
                                        unsigned short* Ws, int t){
    #pragma unroll
    for (int it = 0; it < 8; ++it){
        int g = it * 2048 + t * 8;
        int r = g >> 7, k = g & 127;
        uint4 v = *((const uint4*)(Wt + r * 128 + k));
        *((uint4*)((char*)Ws + swz(r, k * 2))) = v;
    }
}
__device__ __forceinline__ void mfma_pass(const unsigned short* As, const unsigned short* Ws,
                                          int wr, int wc, int l15, int lh, f32x4 acc[2][4]){
    #pragma unroll
    for (int ks = 0; ks < 4; ++ks){
        const int kc = ks * 32 + lh * 8;
        short8 af[2], bfv[4];
        #pragma unroll
        for (int m = 0; m < 2; m++){
            int r = wr + m * 16 + l15;
            af[m] = *((const short8*)((const char*)As + swz(r, kc * 2)));
        }
        #pragma unroll
        for (int n = 0; n < 4; n++){
            int r = wc + n * 16 + l15;
            bfv[n] = *((const short8*)((const char*)Ws + swz(r, kc * 2)));
        }
        #pragma unroll
        for (int m = 0; m < 2; m++)
            #pragma unroll
            for (int n = 0; n < 4; n++)
                acc[m][n] = __builtin_amdgcn_mfma_f32_16x16x32_bf16(af[m], bfv[n], acc[m][n], 0, 0, 0);
    }
}

// ---- gemm0: h = x@W0 + b0 (natural layout [b][j][128] bf16) ----
__global__ __launch_bounds__(256) void k_gemm0(const float* __restrict__ x,
                                               const unsigned short* __restrict__ Wt0,
                                               const float* __restrict__ b0,
                                               unsigned short* __restrict__ h){
    __shared__ unsigned short As[64*128];
    __shared__ unsigned short Ws[128*128];
    const int t = threadIdx.x;
    const int blockRow = blockIdx.x * 64;
    stage_a_f32(x, blockRow, As, t);
    stage_w(Wt0, Ws, t);
    __syncthreads();
    const int lane = t & 63, w = t >> 6;
    const int wr = (w >> 1) * 32, wc = (w & 1) * 64;
    const int l15 = lane & 15, lh = lane >> 4;
    f32x4 acc[2][4];
    #pragma unroll
    for (int m = 0; m < 2; m++) for (int n = 0; n < 4; n++) acc[m][n] = (f32x4)(0.0f);
    mfma_pass(As, Ws, wr, wc, l15, lh, acc);
    #pragma unroll
    for (int m = 0; m < 2; m++){
        #pragma unroll
        for (int rr = 0; rr < 4; rr++){
            int row = blockRow + wr + m * 16 + lh * 4 + rr;
            #pragma unroll
            for (int n = 0; n < 4; n++){
                int col = wc + n * 16 + l15;
                float v = acc[m][n][rr] + b0[col];
                h[(size_t)row * 128 + col] = f2bf(v);
            }
        }
    }
}

// ---- gemm1: t1bf = x@W1a + agg@W1b + b1 (two K=128 phases) ----
__global__ __launch_bounds__(256) void k_gemm1(const float* __restrict__ x,
                                               const unsigned short* __restrict__ agg,
                                               const unsigned short* __restrict__ Wt1a,
                                               const unsigned short* __restrict__ Wt1b,
                                               const float* __restrict__ b1,
                                               unsigned short* __restrict__ t1bf){
    __shared__ unsigned short As[64*128];
    __shared__ unsigned short Ws[128*128];
    const int t = threadIdx.x;
    const int blockRow = blockIdx.x * 64;
    const int lane = t & 63, w = t >> 6;
    const int wr = (w >> 1) * 32, wc = (w & 1) * 64;
    const int l15 = lane & 15, lh = lane >> 4;
    f32x4 acc[2][4];
    #pragma unroll
    for (int m = 0; m < 2; m++) for (int n = 0; n < 4; n++) acc[m][n] = (f32x4)(0.0f);

    stage_a_f32(x, blockRow, As, t);
    stage_w(Wt1a, Ws, t);
    __syncthreads();
    mfma_pass(As, Ws, wr, wc, l15, lh, acc);
    __syncthreads();
    stage_a_bf16(agg, blockRow, As, t);
    stage_w(Wt1b, Ws, t);
    __syncthreads();
    mfma_pass(As, Ws, wr, wc, l15, lh, acc);

    #pragma unroll
    for (int m = 0; m < 2; m++){
        #pragma unroll
        for (int rr = 0; rr < 4; rr++){
            int row = blockRow + wr + m * 16 + lh * 4 + rr;
            #pragma unroll
            for (int n = 0; n < 4; n++){
                int col = wc + n * 16 + l15;
                float v = acc[m][n][rr] + b1[col];
                t1bf[(size_t)row * 128 + col] = f2bf(v);
            }
        }
    }
}

// ---- gemm23: out = gelu(t1bf@W2 + b2)@Wo + bo + x  (f32 out) ----
__global__ __launch_bounds__(256) void k_gemm23(const unsigned short* __restrict__ t1bf,
                                                const unsigned short* __restrict__ Wt2,
                                                const unsigned short* __restrict__ Wto,
                                                const float* __restrict__ b2,
                                                const float* __restrict__ bo,
                                                const float* __restrict__ x,
                                                float* __restrict__ out){
    __shared__ unsigned short As[64*128];     // reused: t1bf tile, then g tile
    __shared__ unsigned short Ws2[128*128];
    __shared__ unsigned short Wso[128*128];
    const int t = threadIdx.x;
    const int blockRow = blockIdx.x * 64;
    const int lane = t & 63, w = t >> 6;
    const int wr = (w >> 1) * 32, wc = (w & 1) * 64;
    const int l15 = lane & 15, lh = lane >> 4;

    stage_a_bf16(t1bf, blockRow, As, t);
    stage_w(Wt2, Ws2, t);
    stage_w(Wto, Wso, t);
    __syncthreads();

    f32x4 acc[2][4];
    #pragma unroll
    for (int m = 0; m < 2; m++) for (int n = 0; n < 4; n++) acc[m][n] = (f32x4)(0.0f);
    mfma_pass(As, Ws2, wr, wc, l15, lh, acc);
    __syncthreads();

    #pragma unroll
    for (int m = 0; m < 2; m++){
        #pragma unroll
        for (int rr = 0; rr < 4; rr++){
            int rl = wr + m * 16 + lh * 4 + rr;
            #pragma unroll
            for (int n = 0; n < 4; n++){
                int col = wc + n * 16 + l15;
                float v = acc[m][n][rr] + b2[col];
                v = 0.5f * v * (1.0f + erff(v * 0.70710678118f));
                *((unsigned short*)((char*)As + swz(rl, col * 2))) = f2bf(v);
            }
        }
    }
    __syncthreads();

    f32x4 acc2[2][4];
    #pragma unroll
    for (int m = 0; m < 2; m++) for (int n = 0; n < 4; n++) acc2[m][n] = (f32x4)(0.0f);
    mfma_pass(As, Wso, wr, wc, l15, lh, acc2);

    #pragma unroll
    for (int m = 0; m < 2; m++){
        #pragma unroll
        for (int rr = 0; rr < 4; rr++){
            int row = blockRow + wr + m * 16 + lh * 4 + rr;
            #pragma unroll
            for (int n = 0; n < 4; n++){
                int col = wc + n * 16 + l15;
                float v = acc2[m][n][rr] + bo[col] + x[(size_t)row * 128 + col];
                out[(size_t)row * 128 + col] = v;
            }
        }
    }
}

extern "C" void kernel_launch(void* const* d_in, const int* in_sizes, int n_in,
                              void* d_out, int out_size, void* d_ws, size_t ws_size,
                              hipStream_t stream) {
    const float* x  = (const float*)d_in[0];
    const int*   ei = (const int*)d_in[1];
    const float* W0 = (const float*)d_in[2];
    const float* b0 = (const float*)d_in[3];
    const float* W1 = (const float*)d_in[4];
    const float* b1 = (const float*)d_in[5];
    const float* W2 = (const float*)d_in[6];
    const float* b2 = (const float*)d_in[7];
    const float* Wo = (const float*)d_in[8];
    const float* bo = (const float*)d_in[9];
    float* out = (float*)d_out;

    char* ws = (char*)d_ws;
    unsigned int* bits   = (unsigned int*)(ws + 0);                  // 2097152
    int*   cols          = (int*)(ws + 2097152);                     // 8388608
    int*   deg           = (int*)(ws + 10485760);                    // 16384
    unsigned short* h    = (unsigned short*)(ws + 10502144);         // 8388608
    unsigned short* aggb = (unsigned short*)(ws + 18890752);         // 8388608
    unsigned short* t1bf = (unsigned short*)(ws + 27279360);         // 8388608
    unsigned short* Wt0  = (unsigned short*)(ws + 35667968);
    unsigned short* Wt1a = (unsigned short*)(ws + 35667968 + 32768);
    unsigned short* Wt1b = (unsigned short*)(ws + 35667968 + 65536);
    unsigned short* Wt2  = (unsigned short*)(ws + 35667968 + 98304);
    unsigned short* Wto  = (unsigned short*)(ws + 35667968 + 131072);

    k_init<<<832, 256, 0, stream>>>((uint4*)bits, W0, W1, W2, Wo, Wt0, Wt1a, Wt1b, Wt2, Wto);
    k_scatter<<<EE / 256, 256, 0, stream>>>(ei, bits);
    k_csr<<<NN, 128, 0, stream>>>(bits, cols, deg);

    k_gemm0<<<M_ROWS / 64, 256, 0, stream>>>(x, Wt0, b0, h);
    k_agg<<<BB * (NN / 4), 256, 0, stream>>>(h, cols, deg, aggb);
    k_gemm1<<<M_ROWS / 64, 256, 0, stream>>>(x, aggb, Wt1a, Wt1b, b1, t1bf);
    k_gemm23<<<M_ROWS / 64, 256, 0, stream>>>(t1bf, Wt2, Wto, b2, bo, x, out);
}

// Round 8
// 77.204 us; speedup vs baseline: 1.4626x; 1.0335x over previous
//
#include <hip/hip_runtime.h>
#include <hip/hip_bf16.h>
#include <math.h>

#define NN 4096
#define BB 8
#define CC 128
#define EE 131072
#define M_ROWS (BB*NN)      // 32768
#define DEG_CAP 512

typedef __attribute__((ext_vector_type(8))) short short8;
typedef __attribute__((ext_vector_type(4))) float f32x4;

__device__ __forceinline__ float bf2f(unsigned int u){
    union { unsigned int i; float f; } v; v.i = u << 16; return v.f;
}
__device__ __forceinline__ unsigned short f2bf(float f){
    union { float f; unsigned int i; } v; v.f = f;
    unsigned int u = v.i;
    unsigned int r = u + 0x7FFFu + ((u >> 16) & 1u);
    return (unsigned short)(r >> 16);
}

// swizzled byte offset for element (row r, k) in a [rows][128] bf16 LDS tile (256B rows)
__device__ __forceinline__ int swz(int r, int k2 /*byte offset in row*/){
    return r * 256 + (k2 ^ ((r & 7) << 4));
}

// ---- fused: zero 2MB bitmap (blocks 0..511) + weight transpose (blocks 512..831) ----
__global__ __launch_bounds__(256) void k_init(uint4* __restrict__ bits4,
                                              const float* __restrict__ W0, const float* __restrict__ W1,
                                              const float* __restrict__ W2, const float* __restrict__ Wo,
                                              unsigned short* __restrict__ Wt0, unsigned short* __restrict__ Wt1a,
                                              unsigned short* __restrict__ Wt1b, unsigned short* __restrict__ Wt2,
                                              unsigned short* __restrict__ Wto){
    int bid = blockIdx.x, t = threadIdx.x;
    if (bid < 512){
        bits4[bid * 256 + t] = (uint4){0u, 0u, 0u, 0u};
        return;
    }
    int idx = (bid - 512) * 256 + t;   // 0..81919
    int s = idx >> 14;
    int e = idx & 16383;
    int n = e >> 7, k = e & 127;
    float v; unsigned short* dst;
    switch (s){
        case 0:  v = W0[k*128+n];        dst = Wt0;  break;
        case 1:  v = W1[k*128+n];        dst = Wt1a; break;
        case 2:  v = W1[(128+k)*128+n];  dst = Wt1b; break;
        case 3:  v = W2[k*128+n];        dst = Wt2;  break;
        default: v = Wo[k*128+n];        dst = Wto;  break;
    }
    dst[n*128+k] = f2bf(v);
}

// ---- scatter edges into bitmap adjacency (atomicOr, dedup free) ----
__global__ __launch_bounds__(256) void k_scatter(const int* __restrict__ ei,
                                                 unsigned int* __restrict__ bits){
    int e = blockIdx.x * blockDim.x + threadIdx.x;
    if (e < EE){
        int u = ei[e], v = ei[EE + e];
        atomicOr(&bits[u * 128 + (v >> 5)], 1u << (v & 31));
        atomicOr(&bits[v * 128 + (u >> 5)], 1u << (u & 31));
    }
}

// ---- compact bitmap row -> padded CSR (skip diagonal), 128 thr/block ----
__global__ __launch_bounds__(128) void k_csr(const unsigned int* __restrict__ bits,
                                             int* __restrict__ cols, int* __restrict__ deg){
    __shared__ int sc[128];
    int i = blockIdx.x, t = threadIdx.x;
    unsigned int w = bits[i * 128 + t];
    if (t == (i >> 5)) w &= ~(1u << (i & 31));   // zero diagonal
    int c = __popc(w);
    sc[t] = c; __syncthreads();
    int val = c;
    for (int off = 1; off < 128; off <<= 1){
        int add = (t >= off) ? sc[t - off] : 0;
        __syncthreads();
        val += add; sc[t] = val;
        __syncthreads();
    }
    int total = sc[127];
    int pos = val - c;   // exclusive prefix
    unsigned int ww = w;
    while (ww){
        int b = __ffs(ww) - 1;
        ww &= ww - 1;
        if (pos < DEG_CAP) cols[(size_t)i * DEG_CAP + pos] = t * 32 + b;
        pos++;
    }
    if (t == 0) deg[i] = total < DEG_CAP ? total : DEG_CAP;
}

// ---- sparse aggregation, XCD-resident per-batch tables ----
// h natural layout [b][j][128] bf16 (256B rows, 1MB per-batch table).
// batch = blockIdx & 7: under round-robin WG->XCD dispatch all blocks of
// batch k land on XCD k -> per-XCD L2 working set = 1MB (fully resident).
// One wave per (b,i). Lane = (sub=lane>>4, li=lane&15): sub selects neighbor
// stream (4 rows in flight per load instr), li covers 8 channels via uint4.
__device__ __forceinline__ void acc8u(uint4 u, float* a){
    a[0] += bf2f(u.x & 0xFFFFu); a[1] += bf2f(u.x >> 16);
    a[2] += bf2f(u.y & 0xFFFFu); a[3] += bf2f(u.y >> 16);
    a[4] += bf2f(u.z & 0xFFFFu); a[5] += bf2f(u.z >> 16);
    a[6] += bf2f(u.w & 0xFFFFu); a[7] += bf2f(u.w >> 16);
}

__global__ __launch_bounds__(256) void k_agg(const unsigned short* __restrict__ h,
                                             const int* __restrict__ cols,
                                             const int* __restrict__ deg,
                                             unsigned short* __restrict__ agg){
    __shared__ int scol[4][DEG_CAP];
    const int t = threadIdx.x;
    const int w = t >> 6, lane = t & 63;
    const int sub = lane >> 4, li = lane & 15;
    const int b = blockIdx.x & 7;                  // XCD-aligned batch
    const int i = ((blockIdx.x >> 3) << 2) + w;    // node
    const int d = deg[i];
    const int* cl = cols + (size_t)i * DEG_CAP;
    for (int q = lane; q < d; q += 64) scol[w][q] = cl[q];
    // same-wave LDS RAW: DS pipe processes ops in order per wave

    const unsigned short* hb = h + (size_t)b * (NN*128) + li * 8;
    float a[8];
    #pragma unroll
    for (int c = 0; c < 8; c++) a[c] = 0.f;

    int n = sub;
    for (; n + 4 < d; n += 8){
        int j0 = scol[w][n], j1 = scol[w][n+4];
        uint4 u0 = *((const uint4*)(hb + ((size_t)j0 << 7)));
        uint4 u1 = *((const uint4*)(hb + ((size_t)j1 << 7)));
        acc8u(u0, a); acc8u(u1, a);
    }
    if (n < d){
        uint4 u0 = *((const uint4*)(hb + ((size_t)scol[w][n] << 7)));
        acc8u(u0, a);
    }

    // reduce across the 4 sub-groups (lanes differing in bits 4,5)
    #pragma unroll
    for (int c = 0; c < 8; c++){
        a[c] += __shfl_xor(a[c], 16);
        a[c] += __shfl_xor(a[c], 32);
    }
    if (sub == 0){
        uint4 o;
        o.x = (unsigned)f2bf(a[0]) | ((unsigned)f2bf(a[1]) << 16);
        o.y = (unsigned)f2bf(a[2]) | ((unsigned)f2bf(a[3]) << 16);
        o.z = (unsigned)f2bf(a[4]) | ((unsigned)f2bf(a[5]) << 16);
        o.w = (unsigned)f2bf(a[6]) | ((unsigned)f2bf(a[7]) << 16);
        *((uint4*)(agg + (size_t)b * (NN*128) + ((size_t)i << 7) + li * 8)) = o;
    }
}

// ===== shared GEMM helpers (64-row tiles, 4 waves: 2x2 wave grid of 32x64) =====
__device__ __forceinline__ void stage_a_bf16(const unsigned short* __restrict__ src, int blockRow,
                                             unsigned short* As, int t){
    #pragma unroll
    for (int it = 0; it < 4; ++it){
        int g = it * 2048 + t * 8;
        int r = g >> 7, k = g & 127;
        uint4 v = *((const uint4*)(src + (size_t)(blockRow + r) * 128 + k));
        *((uint4*)((char*)As + swz(r, k * 2))) = v;
    }
}
__device__ __forceinline__ void stage_a_f32(const float* __restrict__ src, int blockRow,
                                            unsigned short* As, int t){
    #pragma unroll
    for (int it = 0; it < 4; ++it){
        int g = it * 2048 + t * 8;
        int r = g >> 7, k = g & 127;
        const float* p = src + (size_t)(blockRow + r) * 128 + k;
        float4 lo = *((const float4*)p);
        float4 hi = *((const float4*)(p + 4));
        ushort4 w0, w1;
        w0.x = f2bf(lo.x); w0.y = f2bf(lo.y); w0.z = f2bf(lo.z); w0.w = f2bf(lo.w);
        w1.x = f2bf(hi.x); w1.y = f2bf(hi.y); w1.z = f2bf(hi.z); w1.w = f2bf(hi.w);
        char* dst = (char*)As + swz(r, k * 2);
        *((ushort4*)dst) = w0;
        *((ushort4*)(dst + 8)) = w1;
    }
}
__device__ __forceinline__ void stage_w(const unsigned short* __restrict__ Wt,
                                        unsigned short* Ws, int t){
    #pragma unroll
    for (int it = 0; it < 8; ++it){
        int g = it * 2048 + t * 8;
        int r = g >> 7, k = g & 127;
        uint4 v = *((const uint4*)(Wt + r * 128 + k));
        *((uint4*)((char*)Ws + swz(r, k * 2))) = v;
    }
}
__device__ __forceinline__ void mfma_pass(const unsigned short* As, const unsigned short* Ws,
                                          int wr, int wc, int l15, int lh, f32x4 acc[2][4]){
    #pragma unroll
    for (int ks = 0; ks < 4; ++ks){
        const int kc = ks * 32 + lh * 8;
        short8 af[2], bfv[4];
        #pragma unroll
        for (int m = 0; m < 2; m++){
            int r = wr + m * 16 + l15;
            af[m] = *((const short8*)((const char*)As + swz(r, kc * 2)));
        }
        #pragma unroll
        for (int n = 0; n < 4; n++){
            int r = wc + n * 16 + l15;
            bfv[n] = *((const short8*)((const char*)Ws + swz(r, kc * 2)));
        }
        #pragma unroll
        for (int m = 0; m < 2; m++)
            #pragma unroll
            for (int n = 0; n < 4; n++)
                acc[m][n] = __builtin_amdgcn_mfma_f32_16x16x32_bf16(af[m], bfv[n], acc[m][n], 0, 0, 0);
    }
}

// ---- gemm0: h = x@W0 + b0 (natural layout [b][j][128] bf16) ----
__global__ __launch_bounds__(256) void k_gemm0(const float* __restrict__ x,
                                               const unsigned short* __restrict__ Wt0,
                                               const float* __restrict__ b0,
                                               unsigned short* __restrict__ h){
    __shared__ unsigned short As[64*128];
    __shared__ unsigned short Ws[128*128];
    const int t = threadIdx.x;
    const int blockRow = blockIdx.x * 64;
    stage_a_f32(x, blockRow, As, t);
    stage_w(Wt0, Ws, t);
    __syncthreads();
    const int lane = t & 63, w = t >> 6;
    const int wr = (w >> 1) * 32, wc = (w & 1) * 64;
    const int l15 = lane & 15, lh = lane >> 4;
    f32x4 acc[2][4];
    #pragma unroll
    for (int m = 0; m < 2; m++) for (int n = 0; n < 4; n++) acc[m][n] = (f32x4)(0.0f);
    mfma_pass(As, Ws, wr, wc, l15, lh, acc);
    #pragma unroll
    for (int m = 0; m < 2; m++){
        #pragma unroll
        for (int rr = 0; rr < 4; rr++){
            int row = blockRow + wr + m * 16 + lh * 4 + rr;
            #pragma unroll
            for (int n = 0; n < 4; n++){
                int col = wc + n * 16 + l15;
                float v = acc[m][n][rr] + b0[col];
                h[(size_t)row * 128 + col] = f2bf(v);
            }
        }
    }
}

// ---- gemm1: t1bf = x@W1a + agg@W1b + b1 (two K=128 phases) ----
__global__ __launch_bounds__(256) void k_gemm1(const float* __restrict__ x,
                                               const unsigned short* __restrict__ agg,
                                               const unsigned short* __restrict__ Wt1a,
                                               const unsigned short* __restrict__ Wt1b,
                                               const float* __restrict__ b1,
                                               unsigned short* __restrict__ t1bf){
    __shared__ unsigned short As[64*128];
    __shared__ unsigned short Ws[128*128];
    const int t = threadIdx.x;
    const int blockRow = blockIdx.x * 64;
    const int lane = t & 63, w = t >> 6;
    const int wr = (w >> 1) * 32, wc = (w & 1) * 64;
    const int l15 = lane & 15, lh = lane >> 4;
    f32x4 acc[2][4];
    #pragma unroll
    for (int m = 0; m < 2; m++) for (int n = 0; n < 4; n++) acc[m][n] = (f32x4)(0.0f);

    stage_a_f32(x, blockRow, As, t);
    stage_w(Wt1a, Ws, t);
    __syncthreads();
    mfma_pass(As, Ws, wr, wc, l15, lh, acc);
    __syncthreads();
    stage_a_bf16(agg, blockRow, As, t);
    stage_w(Wt1b, Ws, t);
    __syncthreads();
    mfma_pass(As, Ws, wr, wc, l15, lh, acc);

    #pragma unroll
    for (int m = 0; m < 2; m++){
        #pragma unroll
        for (int rr = 0; rr < 4; rr++){
            int row = blockRow + wr + m * 16 + lh * 4 + rr;
            #pragma unroll
            for (int n = 0; n < 4; n++){
                int col = wc + n * 16 + l15;
                float v = acc[m][n][rr] + b1[col];
                t1bf[(size_t)row * 128 + col] = f2bf(v);
            }
        }
    }
}

// ---- gemm23: out = gelu(t1bf@W2 + b2)@Wo + bo + x  (f32 out) ----
__global__ __launch_bounds__(256) void k_gemm23(const unsigned short* __restrict__ t1bf,
                                                const unsigned short* __restrict__ Wt2,
                                                const unsigned short* __restrict__ Wto,
                                                const float* __restrict__ b2,
                                                const float* __restrict__ bo,
                                                const float* __restrict__ x,
                                                float* __restrict__ out){
    __shared__ unsigned short As[64*128];     // reused: t1bf tile, then g tile
    __shared__ unsigned short Ws2[128*128];
    __shared__ unsigned short Wso[128*128];
    const int t = threadIdx.x;
    const int blockRow = blockIdx.x * 64;
    const int lane = t & 63, w = t >> 6;
    const int wr = (w >> 1) * 32, wc = (w & 1) * 64;
    const int l15 = lane & 15, lh = lane >> 4;

    stage_a_bf16(t1bf, blockRow, As, t);
    stage_w(Wt2, Ws2, t);
    stage_w(Wto, Wso, t);
    __syncthreads();

    f32x4 acc[2][4];
    #pragma unroll
    for (int m = 0; m < 2; m++) for (int n = 0; n < 4; n++) acc[m][n] = (f32x4)(0.0f);
    mfma_pass(As, Ws2, wr, wc, l15, lh, acc);
    __syncthreads();

    #pragma unroll
    for (int m = 0; m < 2; m++){
        #pragma unroll
        for (int rr = 0; rr < 4; rr++){
            int rl = wr + m * 16 + lh * 4 + rr;
            #pragma unroll
            for (int n = 0; n < 4; n++){
                int col = wc + n * 16 + l15;
                float v = acc[m][n][rr] + b2[col];
                v = 0.5f * v * (1.0f + erff(v * 0.70710678118f));
                *((unsigned short*)((char*)As + swz(rl, col * 2))) = f2bf(v);
            }
        }
    }
    __syncthreads();

    f32x4 acc2[2][4];
    #pragma unroll
    for (int m = 0; m < 2; m++) for (int n = 0; n < 4; n++) acc2[m][n] = (f32x4)(0.0f);
    mfma_pass(As, Wso, wr, wc, l15, lh, acc2);

    #pragma unroll
    for (int m = 0; m < 2; m++){
        #pragma unroll
        for (int rr = 0; rr < 4; rr++){
            int row = blockRow + wr + m * 16 + lh * 4 + rr;
            #pragma unroll
            for (int n = 0; n < 4; n++){
                int col = wc + n * 16 + l15;
                float v = acc2[m][n][rr] + bo[col] + x[(size_t)row * 128 + col];
                out[(size_t)row * 128 + col] = v;
            }
        }
    }
}

extern "C" void kernel_launch(void* const* d_in, const int* in_sizes, int n_in,
                              void* d_out, int out_size, void* d_ws, size_t ws_size,
                              hipStream_t stream) {
    const float* x  = (const float*)d_in[0];
    const int*   ei = (const int*)d_in[1];
    const float* W0 = (const float*)d_in[2];
    const float* b0 = (const float*)d_in[3];
    const float* W1 = (const float*)d_in[4];
    const float* b1 = (const float*)d_in[5];
    const float* W2 = (const float*)d_in[6];
    const float* b2 = (const float*)d_in[7];
    const float* Wo = (const float*)d_in[8];
    const float* bo = (const float*)d_in[9];
    float* out = (float*)d_out;

    char* ws = (char*)d_ws;
    unsigned int* bits   = (unsigned int*)(ws + 0);                  // 2097152
    int*   cols          = (int*)(ws + 2097152);                     // 8388608
    int*   deg           = (int*)(ws + 10485760);                    // 16384
    unsigned short* h    = (unsigned short*)(ws + 10502144);         // 8388608
    unsigned short* aggb = (unsigned short*)(ws + 18890752);         // 8388608
    unsigned short* t1bf = (unsigned short*)(ws + 27279360);         // 8388608
    unsigned short* Wt0  = (unsigned short*)(ws + 35667968);
    unsigned short* Wt1a = (unsigned short*)(ws + 35667968 + 32768);
    unsigned short* Wt1b = (unsigned short*)(ws + 35667968 + 65536);
    unsigned short* Wt2  = (unsigned short*)(ws + 35667968 + 98304);
    unsigned short* Wto  = (unsigned short*)(ws + 35667968 + 131072);

    k_init<<<832, 256, 0, stream>>>((uint4*)bits, W0, W1, W2, Wo, Wt0, Wt1a, Wt1b, Wt2, Wto);
    k_scatter<<<EE / 256, 256, 0, stream>>>(ei, bits);
    k_csr<<<NN, 128, 0, stream>>>(bits, cols, deg);

    k_gemm0<<<M_ROWS / 64, 256, 0, stream>>>(x, Wt0, b0, h);
    k_agg<<<BB * (NN / 4), 256, 0, stream>>>(h, cols, deg, aggb);
    k_gemm1<<<M_ROWS / 64, 256, 0, stream>>>(x, aggb, Wt1a, Wt1b, b1, t1bf);
    k_gemm23<<<M_ROWS / 64, 256, 0, stream>>>(t1bf, Wt2, Wto, b2, bo, x, out);
}

// Round 9
// 77.133 us; speedup vs baseline: 1.4640x; 1.0009x over previous
//
#include <hip/hip_runtime.h>
#include <hip/hip_bf16.h>
#include <math.h>

#define NN 4096
#define BB 8
#define CC 128
#define EE 131072
#define M_ROWS (BB*NN)      // 32768
#define DEG_CAP 512

typedef __attribute__((ext_vector_type(8))) short short8;
typedef __attribute__((ext_vector_type(4))) float f32x4;

__device__ __forceinline__ float bf2f(unsigned int u){
    union { unsigned int i; float f; } v; v.i = u << 16; return v.f;
}
__device__ __forceinline__ unsigned short f2bf(float f){
    union { float f; unsigned int i; } v; v.f = f;
    unsigned int u = v.i;
    unsigned int r = u + 0x7FFFu + ((u >> 16) & 1u);
    return (unsigned short)(r >> 16);
}

// swizzled byte offset for element (row r, k) in a [rows][128] bf16 LDS tile (256B rows)
__device__ __forceinline__ int swz(int r, int k2 /*byte offset in row*/){
    return r * 256 + (k2 ^ ((r & 7) << 4));
}

// ---- fused init: zero bitmap | x->bf16 | weight transposes ----
// bid 0..511: zero bits; 512..2559: xb = bf16(x); 2560..2879: weights
__global__ __launch_bounds__(256) void k_init(uint4* __restrict__ bits4,
                                              const float* __restrict__ x,
                                              unsigned short* __restrict__ xb,
                                              const float* __restrict__ W0, const float* __restrict__ W1,
                                              const float* __restrict__ W2, const float* __restrict__ Wo,
                                              unsigned short* __restrict__ Wt1a, unsigned short* __restrict__ Wt1b,
                                              unsigned short* __restrict__ Wt2,  unsigned short* __restrict__ Wto,
                                              unsigned short* __restrict__ W0bf){
    int bid = blockIdx.x, t = threadIdx.x;
    if (bid < 512){
        bits4[bid * 256 + t] = (uint4){0u, 0u, 0u, 0u};
        return;
    }
    if (bid < 2560){
        size_t e = (size_t)(bid - 512) * 2048 + t * 8;
        float4 lo = *((const float4*)(x + e));
        float4 hi = *((const float4*)(x + e + 4));
        ushort4 w0, w1;
        w0.x = f2bf(lo.x); w0.y = f2bf(lo.y); w0.z = f2bf(lo.z); w0.w = f2bf(lo.w);
        w1.x = f2bf(hi.x); w1.y = f2bf(hi.y); w1.z = f2bf(hi.z); w1.w = f2bf(hi.w);
        *((ushort4*)(xb + e)) = w0;
        *((ushort4*)(xb + e + 4)) = w1;
        return;
    }
    int idx = (bid - 2560) * 256 + t;   // 0..81919
    int s = idx >> 14;
    int e = idx & 16383;
    int n = e >> 7, k = e & 127;
    float v; unsigned short* dst;
    switch (s){
        case 0:  v = W1[k*128+n];        dst = Wt1a; break;
        case 1:  v = W1[(128+k)*128+n];  dst = Wt1b; break;
        case 2:  v = W2[k*128+n];        dst = Wt2;  break;
        case 3:  v = Wo[k*128+n];        dst = Wto;  break;
        default: v = W0[n*128+k];        dst = W0bf; break;   // natural layout
    }
    dst[n*128+k] = f2bf(v);
}

// ---- scatter edges into bitmap adjacency (atomicOr, dedup free) ----
__global__ __launch_bounds__(256) void k_scatter(const int* __restrict__ ei,
                                                 unsigned int* __restrict__ bits){
    int e = blockIdx.x * blockDim.x + threadIdx.x;
    if (e < EE){
        int u = ei[e], v = ei[EE + e];
        atomicOr(&bits[u * 128 + (v >> 5)], 1u << (v & 31));
        atomicOr(&bits[v * 128 + (u >> 5)], 1u << (u & 31));
    }
}

// ---- compact bitmap row -> padded CSR (skip diagonal), 128 thr/block ----
__global__ __launch_bounds__(128) void k_csr(const unsigned int* __restrict__ bits,
                                             int* __restrict__ cols, int* __restrict__ deg){
    __shared__ int sc[128];
    int i = blockIdx.x, t = threadIdx.x;
    unsigned int w = bits[i * 128 + t];
    if (t == (i >> 5)) w &= ~(1u << (i & 31));   // zero diagonal
    int c = __popc(w);
    sc[t] = c; __syncthreads();
    int val = c;
    for (int off = 1; off < 128; off <<= 1){
        int add = (t >= off) ? sc[t - off] : 0;
        __syncthreads();
        val += add; sc[t] = val;
        __syncthreads();
    }
    int total = sc[127];
    int pos = val - c;   // exclusive prefix
    unsigned int ww = w;
    while (ww){
        int b = __ffs(ww) - 1;
        ww &= ww - 1;
        if (pos < DEG_CAP) cols[(size_t)i * DEG_CAP + pos] = t * 32 + b;
        pos++;
    }
    if (t == 0) deg[i] = total < DEG_CAP ? total : DEG_CAP;
}

// ---- stage 128x128 bf16 weight into LDS (swizzled) ----
__device__ __forceinline__ void stage_w(const unsigned short* __restrict__ Wt,
                                        unsigned short* Ws, int t){
    #pragma unroll
    for (int it = 0; it < 8; ++it){
        int g = it * 2048 + t * 8;
        int r = g >> 7, k = g & 127;
        uint4 v = *((const uint4*)(Wt + r * 128 + k));
        *((uint4*)((char*)Ws + swz(r, k * 2))) = v;
    }
}
__device__ __forceinline__ void stage_a_bf16(const unsigned short* __restrict__ src, int blockRow,
                                             unsigned short* As, int t){
    #pragma unroll
    for (int it = 0; it < 4; ++it){
        int g = it * 2048 + t * 8;
        int r = g >> 7, k = g & 127;
        uint4 v = *((const uint4*)(src + (size_t)(blockRow + r) * 128 + k));
        *((uint4*)((char*)As + swz(r, k * 2))) = v;
    }
}
__device__ __forceinline__ void mfma_pass(const unsigned short* As, const unsigned short* Ws,
                                          int wr, int wc, int l15, int lh, f32x4 acc[2][4]){
    #pragma unroll
    for (int ks = 0; ks < 4; ++ks){
        const int kc = ks * 32 + lh * 8;
        short8 af[2], bfv[4];
        #pragma unroll
        for (int m = 0; m < 2; m++){
            int r = wr + m * 16 + l15;
            af[m] = *((const short8*)((const char*)As + swz(r, kc * 2)));
        }
        #pragma unroll
        for (int n = 0; n < 4; n++){
            int r = wc + n * 16 + l15;
            bfv[n] = *((const short8*)((const char*)Ws + swz(r, kc * 2)));
        }
        #pragma unroll
        for (int m = 0; m < 2; m++)
            #pragma unroll
            for (int n = 0; n < 4; n++)
                acc[m][n] = __builtin_amdgcn_mfma_f32_16x16x32_bf16(af[m], bfv[n], acc[m][n], 0, 0, 0);
    }
}

// ---- wprod (1 block): Wtu[n][k] = (W0@W1b)[k][n] bf16;  c1[n] = b0@W1b ----
__global__ __launch_bounds__(256) void k_wprod(const unsigned short* __restrict__ W0bf,
                                               const unsigned short* __restrict__ Wt1b,
                                               const float* __restrict__ b0,
                                               const float* __restrict__ W1,
                                               unsigned short* __restrict__ Wtu,
                                               float* __restrict__ c1){
    __shared__ unsigned short As[128*128];
    __shared__ unsigned short Ws[128*128];
    const int t = threadIdx.x;
    stage_w(W0bf, As, t);    // A[r][m] = W0[r][m]
    stage_w(Wt1b, Ws, t);    // Ws[c][m] = W1b[m][c]
    __syncthreads();
    const int lane = t & 63, w = t >> 6;
    const int wr = w * 32;
    const int l15 = lane & 15, lh = lane >> 4;
    f32x4 acc[2][8];
    #pragma unroll
    for (int m = 0; m < 2; m++) for (int n = 0; n < 8; n++) acc[m][n] = (f32x4)(0.0f);
    #pragma unroll
    for (int ks = 0; ks < 4; ++ks){
        const int kc = ks * 32 + lh * 8;
        short8 af[2], bfv[8];
        #pragma unroll
        for (int m = 0; m < 2; m++){
            int r = wr + m * 16 + l15;
            af[m] = *((const short8*)((const char*)As + swz(r, kc * 2)));
        }
        #pragma unroll
        for (int n = 0; n < 8; n++){
            int r = n * 16 + l15;
            bfv[n] = *((const short8*)((const char*)Ws + swz(r, kc * 2)));
        }
        #pragma unroll
        for (int m = 0; m < 2; m++)
            #pragma unroll
            for (int n = 0; n < 8; n++)
                acc[m][n] = __builtin_amdgcn_mfma_f32_16x16x32_bf16(af[m], bfv[n], acc[m][n], 0, 0, 0);
    }
    // D[r][c] = (W0@W1b)[r][c]; store transposed: Wtu[c*128 + r]
    #pragma unroll
    for (int m = 0; m < 2; m++){
        #pragma unroll
        for (int rr = 0; rr < 4; rr++){
            int r = wr + m * 16 + lh * 4 + rr;
            #pragma unroll
            for (int n = 0; n < 8; n++){
                int c = n * 16 + l15;
                Wtu[c * 128 + r] = f2bf(acc[m][n][rr]);
            }
        }
    }
    // c1[n] = sum_k b0[k] * W1[(128+k)*128 + n]
    if (t < 128){
        float s = 0.f;
        #pragma unroll 8
        for (int k = 0; k < 128; k++)
            s += b0[k] * W1[(size_t)(128 + k) * 128 + t];
        c1[t] = s;
    }
}

// ---- sparse aggregation on xb (XCD-resident per-batch 1MB tables): u = A.x ----
__device__ __forceinline__ void acc8u(uint4 u, float* a){
    a[0] += bf2f(u.x & 0xFFFFu); a[1] += bf2f(u.x >> 16);
    a[2] += bf2f(u.y & 0xFFFFu); a[3] += bf2f(u.y >> 16);
    a[4] += bf2f(u.z & 0xFFFFu); a[5] += bf2f(u.z >> 16);
    a[6] += bf2f(u.w & 0xFFFFu); a[7] += bf2f(u.w >> 16);
}

__global__ __launch_bounds__(256) void k_agg(const unsigned short* __restrict__ h,
                                             const int* __restrict__ cols,
                                             const int* __restrict__ deg,
                                             unsigned short* __restrict__ agg){
    __shared__ int scol[4][DEG_CAP];
    const int t = threadIdx.x;
    const int w = t >> 6, lane = t & 63;
    const int sub = lane >> 4, li = lane & 15;
    const int b = blockIdx.x & 7;                  // XCD-aligned batch
    const int i = ((blockIdx.x >> 3) << 2) + w;    // node
    const int d = deg[i];
    const int* cl = cols + (size_t)i * DEG_CAP;
    for (int q = lane; q < d; q += 64) scol[w][q] = cl[q];

    const unsigned short* hb = h + (size_t)b * (NN*128) + li * 8;
    float a[8];
    #pragma unroll
    for (int c = 0; c < 8; c++) a[c] = 0.f;

    int n = sub;
    for (; n + 4 < d; n += 8){
        int j0 = scol[w][n], j1 = scol[w][n+4];
        uint4 u0 = *((const uint4*)(hb + ((size_t)j0 << 7)));
        uint4 u1 = *((const uint4*)(hb + ((size_t)j1 << 7)));
        acc8u(u0, a); acc8u(u1, a);
    }
    if (n < d){
        uint4 u0 = *((const uint4*)(hb + ((size_t)scol[w][n] << 7)));
        acc8u(u0, a);
    }
    #pragma unroll
    for (int c = 0; c < 8; c++){
        a[c] += __shfl_xor(a[c], 16);
        a[c] += __shfl_xor(a[c], 32);
    }
    if (sub == 0){
        uint4 o;
        o.x = (unsigned)f2bf(a[0]) | ((unsigned)f2bf(a[1]) << 16);
        o.y = (unsigned)f2bf(a[2]) | ((unsigned)f2bf(a[3]) << 16);
        o.z = (unsigned)f2bf(a[4]) | ((unsigned)f2bf(a[5]) << 16);
        o.w = (unsigned)f2bf(a[6]) | ((unsigned)f2bf(a[7]) << 16);
        *((uint4*)(agg + (size_t)b * (NN*128) + ((size_t)i << 7) + li * 8)) = o;
    }
}

// ---- fused MLP: out = gelu((xb@W1a + u@Wtu + deg*c1 + b1)@W2 + b2)@Wo + bo + x ----
__global__ __launch_bounds__(256) void k_mlp(const unsigned short* __restrict__ xb,
                                             const unsigned short* __restrict__ u,
                                             const unsigned short* __restrict__ Wt1a,
                                             const unsigned short* __restrict__ Wtu,
                                             const unsigned short* __restrict__ Wt2,
                                             const unsigned short* __restrict__ Wto,
                                             const float* __restrict__ c1,
                                             const float* __restrict__ b1,
                                             const float* __restrict__ b2,
                                             const float* __restrict__ bo,
                                             const int* __restrict__ deg,
                                             const float* __restrict__ x,
                                             float* __restrict__ out){
    __shared__ unsigned short As[64*128];
    __shared__ unsigned short Ws[128*128];
    const int t = threadIdx.x;
    const int blockRow = blockIdx.x * 64;
    const int lane = t & 63, w = t >> 6;
    const int wr = (w >> 1) * 32, wc = (w & 1) * 64;
    const int l15 = lane & 15, lh = lane >> 4;

    f32x4 acc[2][4];
    #pragma unroll
    for (int m = 0; m < 2; m++) for (int n = 0; n < 4; n++) acc[m][n] = (f32x4)(0.0f);

    // pass1: xb @ W1a
    stage_a_bf16(xb, blockRow, As, t);
    stage_w(Wt1a, Ws, t);
    __syncthreads();
    mfma_pass(As, Ws, wr, wc, l15, lh, acc);
    __syncthreads();
    // pass2: + u @ Wtu
    stage_a_bf16(u, blockRow, As, t);
    stage_w(Wtu, Ws, t);
    __syncthreads();
    mfma_pass(As, Ws, wr, wc, l15, lh, acc);
    __syncthreads();

    // t1 = acc + b1 + deg*c1 -> As (bf16, swizzled); stage W2
    #pragma unroll
    for (int m = 0; m < 2; m++){
        #pragma unroll
        for (int rr = 0; rr < 4; rr++){
            int rl = wr + m * 16 + lh * 4 + rr;
            int node = (blockRow + rl) & (NN - 1);
            float degf = (float)deg[node];
            #pragma unroll
            for (int n = 0; n < 4; n++){
                int col = wc + n * 16 + l15;
                float v = acc[m][n][rr] + b1[col] + degf * c1[col];
                *((unsigned short*)((char*)As + swz(rl, col * 2))) = f2bf(v);
            }
        }
    }
    stage_w(Wt2, Ws, t);
    __syncthreads();

    // pass3: t1 @ W2
    f32x4 acc2[2][4];
    #pragma unroll
    for (int m = 0; m < 2; m++) for (int n = 0; n < 4; n++) acc2[m][n] = (f32x4)(0.0f);
    mfma_pass(As, Ws, wr, wc, l15, lh, acc2);
    __syncthreads();

    // g = gelu(acc2 + b2) -> As; stage Wo
    #pragma unroll
    for (int m = 0; m < 2; m++){
        #pragma unroll
        for (int rr = 0; rr < 4; rr++){
            int rl = wr + m * 16 + lh * 4 + rr;
            #pragma unroll
            for (int n = 0; n < 4; n++){
                int col = wc + n * 16 + l15;
                float v = acc2[m][n][rr] + b2[col];
                v = 0.5f * v * (1.0f + erff(v * 0.70710678118f));
                *((unsigned short*)((char*)As + swz(rl, col * 2))) = f2bf(v);
            }
        }
    }
    stage_w(Wto, Ws, t);
    __syncthreads();

    // pass4: g @ Wo; out = + bo + x
    f32x4 acc3[2][4];
    #pragma unroll
    for (int m = 0; m < 2; m++) for (int n = 0; n < 4; n++) acc3[m][n] = (f32x4)(0.0f);
    mfma_pass(As, Ws, wr, wc, l15, lh, acc3);

    #pragma unroll
    for (int m = 0; m < 2; m++){
        #pragma unroll
        for (int rr = 0; rr < 4; rr++){
            int row = blockRow + wr + m * 16 + lh * 4 + rr;
            #pragma unroll
            for (int n = 0; n < 4; n++){
                int col = wc + n * 16 + l15;
                float v = acc3[m][n][rr] + bo[col] + x[(size_t)row * 128 + col];
                out[(size_t)row * 128 + col] = v;
            }
        }
    }
}

extern "C" void kernel_launch(void* const* d_in, const int* in_sizes, int n_in,
                              void* d_out, int out_size, void* d_ws, size_t ws_size,
                              hipStream_t stream) {
    const float* x  = (const float*)d_in[0];
    const int*   ei = (const int*)d_in[1];
    const float* W0 = (const float*)d_in[2];
    const float* b0 = (const float*)d_in[3];
    const float* W1 = (const float*)d_in[4];
    const float* b1 = (const float*)d_in[5];
    const float* W2 = (const float*)d_in[6];
    const float* b2 = (const float*)d_in[7];
    const float* Wo = (const float*)d_in[8];
    const float* bo = (const float*)d_in[9];
    float* out = (float*)d_out;

    char* ws = (char*)d_ws;
    unsigned int* bits   = (unsigned int*)(ws + 0);                  // 2 MB
    int*   cols          = (int*)(ws + 2097152);                     // 8 MB
    int*   deg           = (int*)(ws + 10485760);                    // 16 KB
    unsigned short* xb   = (unsigned short*)(ws + 10502144);         // 8 MB
    unsigned short* ubuf = (unsigned short*)(ws + 18890752);         // 8 MB
    unsigned short* Wt1a = (unsigned short*)(ws + 27279360);
    unsigned short* Wt1b = (unsigned short*)(ws + 27279360 + 32768);
    unsigned short* Wt2  = (unsigned short*)(ws + 27279360 + 65536);
    unsigned short* Wto  = (unsigned short*)(ws + 27279360 + 98304);
    unsigned short* W0bf = (unsigned short*)(ws + 27279360 + 131072);
    unsigned short* Wtu  = (unsigned short*)(ws + 27279360 + 163840);
    float* c1            = (float*)(ws + 27279360 + 196608);

    k_init<<<2880, 256, 0, stream>>>((uint4*)bits, x, xb, W0, W1, W2, Wo,
                                     Wt1a, Wt1b, Wt2, Wto, W0bf);
    k_scatter<<<EE / 256, 256, 0, stream>>>(ei, bits);
    k_csr<<<NN, 128, 0, stream>>>(bits, cols, deg);
    k_wprod<<<1, 256, 0, stream>>>(W0bf, Wt1b, b0, W1, Wtu, c1);
    k_agg<<<BB * (NN / 4), 256, 0, stream>>>(xb, cols, deg, ubuf);
    k_mlp<<<M_ROWS / 64, 256, 0, stream>>>(xb, ubuf, Wt1a, Wtu, Wt2, Wto,
                                           c1, b1, b2, bo, deg, x, out);
}

// Round 10
// 77.100 us; speedup vs baseline: 1.4646x; 1.0004x over previous
//
#include <hip/hip_runtime.h>
#include <hip/hip_bf16.h>
#include <math.h>

#define NN 4096
#define BB 8
#define CC 128
#define EE 131072
#define M_ROWS (BB*NN)      // 32768
#define DEG_CAP 512

typedef __attribute__((ext_vector_type(8))) short short8;
typedef __attribute__((ext_vector_type(4))) float f32x4;

__device__ __forceinline__ float bf2f(unsigned int u){
    union { unsigned int i; float f; } v; v.i = u << 16; return v.f;
}
__device__ __forceinline__ unsigned short f2bf(float f){
    union { float f; unsigned int i; } v; v.f = f;
    unsigned int u = v.i;
    unsigned int r = u + 0x7FFFu + ((u >> 16) & 1u);
    return (unsigned short)(r >> 16);
}

// swizzled byte offset for element (row r, k) in a [rows][128] bf16 LDS tile (256B rows)
__device__ __forceinline__ int swz(int r, int k2 /*byte offset in row*/){
    return r * 256 + (k2 ^ ((r & 7) << 4));
}

// ---- fused init: zero bitmap | x->bf16 | weight transposes ----
// bid 0..511: zero bits; 512..2559: xb = bf16(x); 2560..2879: weights
__global__ __launch_bounds__(256) void k_init(uint4* __restrict__ bits4,
                                              const float* __restrict__ x,
                                              unsigned short* __restrict__ xb,
                                              const float* __restrict__ W0, const float* __restrict__ W1,
                                              const float* __restrict__ W2, const float* __restrict__ Wo,
                                              unsigned short* __restrict__ Wt1a, unsigned short* __restrict__ Wt1b,
                                              unsigned short* __restrict__ Wt2,  unsigned short* __restrict__ Wto,
                                              unsigned short* __restrict__ W0bf){
    int bid = blockIdx.x, t = threadIdx.x;
    if (bid < 512){
        bits4[bid * 256 + t] = (uint4){0u, 0u, 0u, 0u};
        return;
    }
    if (bid < 2560){
        size_t e = (size_t)(bid - 512) * 2048 + t * 8;
        float4 lo = *((const float4*)(x + e));
        float4 hi = *((const float4*)(x + e + 4));
        ushort4 w0, w1;
        w0.x = f2bf(lo.x); w0.y = f2bf(lo.y); w0.z = f2bf(lo.z); w0.w = f2bf(lo.w);
        w1.x = f2bf(hi.x); w1.y = f2bf(hi.y); w1.z = f2bf(hi.z); w1.w = f2bf(hi.w);
        *((ushort4*)(xb + e)) = w0;
        *((ushort4*)(xb + e + 4)) = w1;
        return;
    }
    int idx = (bid - 2560) * 256 + t;   // 0..81919
    int s = idx >> 14;
    int e = idx & 16383;
    int n = e >> 7, k = e & 127;
    float v; unsigned short* dst;
    switch (s){
        case 0:  v = W1[k*128+n];        dst = Wt1a; break;
        case 1:  v = W1[(128+k)*128+n];  dst = Wt1b; break;
        case 2:  v = W2[k*128+n];        dst = Wt2;  break;
        case 3:  v = Wo[k*128+n];        dst = Wto;  break;
        default: v = W0[n*128+k];        dst = W0bf; break;   // natural layout
    }
    dst[n*128+k] = f2bf(v);
}

// ---- stage 128x128 bf16 weight into LDS (swizzled) ----
__device__ __forceinline__ void stage_w(const unsigned short* __restrict__ Wt,
                                        unsigned short* Ws, int t){
    #pragma unroll
    for (int it = 0; it < 8; ++it){
        int g = it * 2048 + t * 8;
        int r = g >> 7, k = g & 127;
        uint4 v = *((const uint4*)(Wt + r * 128 + k));
        *((uint4*)((char*)Ws + swz(r, k * 2))) = v;
    }
}
__device__ __forceinline__ void stage_a_bf16(const unsigned short* __restrict__ src, int blockRow,
                                             unsigned short* As, int t){
    #pragma unroll
    for (int it = 0; it < 4; ++it){
        int g = it * 2048 + t * 8;
        int r = g >> 7, k = g & 127;
        uint4 v = *((const uint4*)(src + (size_t)(blockRow + r) * 128 + k));
        *((uint4*)((char*)As + swz(r, k * 2))) = v;
    }
}
__device__ __forceinline__ void mfma_pass(const unsigned short* As, const unsigned short* Ws,
                                          int wr, int wc, int l15, int lh, f32x4 acc[2][4]){
    #pragma unroll
    for (int ks = 0; ks < 4; ++ks){
        const int kc = ks * 32 + lh * 8;
        short8 af[2], bfv[4];
        #pragma unroll
        for (int m = 0; m < 2; m++){
            int r = wr + m * 16 + l15;
            af[m] = *((const short8*)((const char*)As + swz(r, kc * 2)));
        }
        #pragma unroll
        for (int n = 0; n < 4; n++){
            int r = wc + n * 16 + l15;
            bfv[n] = *((const short8*)((const char*)Ws + swz(r, kc * 2)));
        }
        #pragma unroll
        for (int m = 0; m < 2; m++)
            #pragma unroll
            for (int n = 0; n < 4; n++)
                acc[m][n] = __builtin_amdgcn_mfma_f32_16x16x32_bf16(af[m], bfv[n], acc[m][n], 0, 0, 0);
    }
}

// ---- fused: scatter edges (blocks 0..511) | wprod (block 512) ----
// wprod: Wtu[n][k] = (W0@W1b)[k][n] bf16; c1[n] = b0@W1b
__global__ __launch_bounds__(256) void k_scatter(const int* __restrict__ ei,
                                                 unsigned int* __restrict__ bits,
                                                 const unsigned short* __restrict__ W0bf,
                                                 const unsigned short* __restrict__ Wt1b,
                                                 const float* __restrict__ b0,
                                                 const float* __restrict__ W1,
                                                 unsigned short* __restrict__ Wtu,
                                                 float* __restrict__ c1){
    const int bid = blockIdx.x, t = threadIdx.x;
    if (bid < 512){
        int e = bid * 256 + t;
        int u = ei[e], v = ei[EE + e];
        atomicOr(&bits[u * 128 + (v >> 5)], 1u << (v & 31));
        atomicOr(&bits[v * 128 + (u >> 5)], 1u << (u & 31));
        return;
    }
    // ---- wprod block ----
    __shared__ unsigned short As[128*128];
    __shared__ unsigned short Ws[128*128];
    stage_w(W0bf, As, t);    // A[r][m] = W0[r][m]
    stage_w(Wt1b, Ws, t);    // Ws[c][m] = W1b[m][c]
    __syncthreads();
    const int lane = t & 63, w = t >> 6;
    const int wr = w * 32;
    const int l15 = lane & 15, lh = lane >> 4;
    f32x4 acc[2][8];
    #pragma unroll
    for (int m = 0; m < 2; m++) for (int n = 0; n < 8; n++) acc[m][n] = (f32x4)(0.0f);
    #pragma unroll
    for (int ks = 0; ks < 4; ++ks){
        const int kc = ks * 32 + lh * 8;
        short8 af[2], bfv[8];
        #pragma unroll
        for (int m = 0; m < 2; m++){
            int r = wr + m * 16 + l15;
            af[m] = *((const short8*)((const char*)As + swz(r, kc * 2)));
        }
        #pragma unroll
        for (int n = 0; n < 8; n++){
            int r = n * 16 + l15;
            bfv[n] = *((const short8*)((const char*)Ws + swz(r, kc * 2)));
        }
        #pragma unroll
        for (int m = 0; m < 2; m++)
            #pragma unroll
            for (int n = 0; n < 8; n++)
                acc[m][n] = __builtin_amdgcn_mfma_f32_16x16x32_bf16(af[m], bfv[n], acc[m][n], 0, 0, 0);
    }
    // D[r][c] = (W0@W1b)[r][c]; store transposed: Wtu[c*128 + r]
    #pragma unroll
    for (int m = 0; m < 2; m++){
        #pragma unroll
        for (int rr = 0; rr < 4; rr++){
            int r = wr + m * 16 + lh * 4 + rr;
            #pragma unroll
            for (int n = 0; n < 8; n++){
                int c = n * 16 + l15;
                Wtu[c * 128 + r] = f2bf(acc[m][n][rr]);
            }
        }
    }
    // c1[n] = sum_k b0[k] * W1[(128+k)*128 + n]
    if (t < 128){
        float s = 0.f;
        #pragma unroll 8
        for (int k = 0; k < 128; k++)
            s += b0[k] * W1[(size_t)(128 + k) * 128 + t];
        c1[t] = s;
    }
}

// ---- compact bitmap row -> padded CSR (uint16 cols, skip diagonal) ----
__global__ __launch_bounds__(128) void k_csr(const unsigned int* __restrict__ bits,
                                             unsigned short* __restrict__ cols, int* __restrict__ deg){
    __shared__ int sc[128];
    int i = blockIdx.x, t = threadIdx.x;
    unsigned int w = bits[i * 128 + t];
    if (t == (i >> 5)) w &= ~(1u << (i & 31));   // zero diagonal
    int c = __popc(w);
    sc[t] = c; __syncthreads();
    int val = c;
    for (int off = 1; off < 128; off <<= 1){
        int add = (t >= off) ? sc[t - off] : 0;
        __syncthreads();
        val += add; sc[t] = val;
        __syncthreads();
    }
    int total = sc[127];
    int pos = val - c;   // exclusive prefix
    unsigned int ww = w;
    while (ww){
        int b = __ffs(ww) - 1;
        ww &= ww - 1;
        if (pos < DEG_CAP) cols[(size_t)i * DEG_CAP + pos] = (unsigned short)(t * 32 + b);
        pos++;
    }
    if (t == 0) deg[i] = total < DEG_CAP ? total : DEG_CAP;
}

// ---- sparse aggregation on xb (XCD-resident per-batch 1MB tables): u = A.x ----
__device__ __forceinline__ void acc8u(uint4 u, float* a){
    a[0] += bf2f(u.x & 0xFFFFu); a[1] += bf2f(u.x >> 16);
    a[2] += bf2f(u.y & 0xFFFFu); a[3] += bf2f(u.y >> 16);
    a[4] += bf2f(u.z & 0xFFFFu); a[5] += bf2f(u.z >> 16);
    a[6] += bf2f(u.w & 0xFFFFu); a[7] += bf2f(u.w >> 16);
}

__global__ __launch_bounds__(256) void k_agg(const unsigned short* __restrict__ h,
                                             const unsigned short* __restrict__ cols,
                                             const int* __restrict__ deg,
                                             unsigned short* __restrict__ agg){
    __shared__ unsigned short scol[4][DEG_CAP];
    const int t = threadIdx.x;
    const int w = t >> 6, lane = t & 63;
    const int sub = lane >> 4, li = lane & 15;
    const int b = blockIdx.x & 7;                  // XCD-aligned batch
    const int i = ((blockIdx.x >> 3) << 2) + w;    // node
    const int d = deg[i];
    const unsigned short* cl = cols + (size_t)i * DEG_CAP;
    for (int q = lane; q < d; q += 64) scol[w][q] = cl[q];

    const unsigned short* hb = h + (size_t)b * (NN*128) + li * 8;
    float a[8];
    #pragma unroll
    for (int c = 0; c < 8; c++) a[c] = 0.f;

    int n = sub;
    for (; n + 4 < d; n += 8){
        int j0 = scol[w][n], j1 = scol[w][n+4];
        uint4 u0 = *((const uint4*)(hb + ((size_t)j0 << 7)));
        uint4 u1 = *((const uint4*)(hb + ((size_t)j1 << 7)));
        acc8u(u0, a); acc8u(u1, a);
    }
    if (n < d){
        uint4 u0 = *((const uint4*)(hb + ((size_t)scol[w][n] << 7)));
        acc8u(u0, a);
    }
    #pragma unroll
    for (int c = 0; c < 8; c++){
        a[c] += __shfl_xor(a[c], 16);
        a[c] += __shfl_xor(a[c], 32);
    }
    if (sub == 0){
        uint4 o;
        o.x = (unsigned)f2bf(a[0]) | ((unsigned)f2bf(a[1]) << 16);
        o.y = (unsigned)f2bf(a[2]) | ((unsigned)f2bf(a[3]) << 16);
        o.z = (unsigned)f2bf(a[4]) | ((unsigned)f2bf(a[5]) << 16);
        o.w = (unsigned)f2bf(a[6]) | ((unsigned)f2bf(a[7]) << 16);
        *((uint4*)(agg + (size_t)b * (NN*128) + ((size_t)i << 7) + li * 8)) = o;
    }
}

// ---- fused MLP: out = gelu((xb@W1a + u@Wtu + deg*c1 + b1)@W2 + b2)@Wo + bo + xb ----
// residual seeded from the LDS xb tile after pass1 (no f32 x read at all)
__global__ __launch_bounds__(256) void k_mlp(const unsigned short* __restrict__ xb,
                                             const unsigned short* __restrict__ u,
                                             const unsigned short* __restrict__ Wt1a,
                                             const unsigned short* __restrict__ Wtu,
                                             const unsigned short* __restrict__ Wt2,
                                             const unsigned short* __restrict__ Wto,
                                             const float* __restrict__ c1,
                                             const float* __restrict__ b1,
                                             const float* __restrict__ b2,
                                             const float* __restrict__ bo,
                                             const int* __restrict__ deg,
                                             float* __restrict__ out){
    __shared__ unsigned short As[64*128];
    __shared__ unsigned short Ws[128*128];
    const int t = threadIdx.x;
    const int blockRow = blockIdx.x * 64;
    const int lane = t & 63, w = t >> 6;
    const int wr = (w >> 1) * 32, wc = (w & 1) * 64;
    const int l15 = lane & 15, lh = lane >> 4;

    f32x4 acc[2][4];
    #pragma unroll
    for (int m = 0; m < 2; m++) for (int n = 0; n < 4; n++) acc[m][n] = (f32x4)(0.0f);

    // pass1: xb @ W1a
    stage_a_bf16(xb, blockRow, As, t);
    stage_w(Wt1a, Ws, t);
    __syncthreads();
    mfma_pass(As, Ws, wr, wc, l15, lh, acc);

    // seed acc3 = residual (bf16 x from LDS tile) + bo, before As is overwritten
    f32x4 acc3[2][4];
    #pragma unroll
    for (int m = 0; m < 2; m++){
        #pragma unroll
        for (int rr = 0; rr < 4; rr++){
            int rl = wr + m * 16 + lh * 4 + rr;
            #pragma unroll
            for (int n = 0; n < 4; n++){
                int col = wc + n * 16 + l15;
                unsigned int us = *((const unsigned short*)((const char*)As + swz(rl, col * 2)));
                acc3[m][n][rr] = bf2f(us) + bo[col];
            }
        }
    }
    __syncthreads();

    // pass2: + u @ Wtu
    stage_a_bf16(u, blockRow, As, t);
    stage_w(Wtu, Ws, t);
    __syncthreads();
    mfma_pass(As, Ws, wr, wc, l15, lh, acc);
    __syncthreads();

    // t1 = acc + b1 + deg*c1 -> As (bf16, swizzled); stage W2
    #pragma unroll
    for (int m = 0; m < 2; m++){
        #pragma unroll
        for (int rr = 0; rr < 4; rr++){
            int rl = wr + m * 16 + lh * 4 + rr;
            int node = (blockRow + rl) & (NN - 1);
            float degf = (float)deg[node];
            #pragma unroll
            for (int n = 0; n < 4; n++){
                int col = wc + n * 16 + l15;
                float v = acc[m][n][rr] + b1[col] + degf * c1[col];
                *((unsigned short*)((char*)As + swz(rl, col * 2))) = f2bf(v);
            }
        }
    }
    stage_w(Wt2, Ws, t);
    __syncthreads();

    // pass3: t1 @ W2
    f32x4 acc2[2][4];
    #pragma unroll
    for (int m = 0; m < 2; m++) for (int n = 0; n < 4; n++) acc2[m][n] = (f32x4)(0.0f);
    mfma_pass(As, Ws, wr, wc, l15, lh, acc2);
    __syncthreads();

    // g = gelu(acc2 + b2) -> As; stage Wo
    #pragma unroll
    for (int m = 0; m < 2; m++){
        #pragma unroll
        for (int rr = 0; rr < 4; rr++){
            int rl = wr + m * 16 + lh * 4 + rr;
            #pragma unroll
            for (int n = 0; n < 4; n++){
                int col = wc + n * 16 + l15;
                float v = acc2[m][n][rr] + b2[col];
                v = 0.5f * v * (1.0f + erff(v * 0.70710678118f));
                *((unsigned short*)((char*)As + swz(rl, col * 2))) = f2bf(v);
            }
        }
    }
    stage_w(Wto, Ws, t);
    __syncthreads();

    // pass4: acc3 += g @ Wo  (residual+bo pre-seeded)
    mfma_pass(As, Ws, wr, wc, l15, lh, acc3);

    #pragma unroll
    for (int m = 0; m < 2; m++){
        #pragma unroll
        for (int rr = 0; rr < 4; rr++){
            int row = blockRow + wr + m * 16 + lh * 4 + rr;
            #pragma unroll
            for (int n = 0; n < 4; n++){
                int col = wc + n * 16 + l15;
                out[(size_t)row * 128 + col] = acc3[m][n][rr];
            }
        }
    }
}

extern "C" void kernel_launch(void* const* d_in, const int* in_sizes, int n_in,
                              void* d_out, int out_size, void* d_ws, size_t ws_size,
                              hipStream_t stream) {
    const float* x  = (const float*)d_in[0];
    const int*   ei = (const int*)d_in[1];
    const float* W0 = (const float*)d_in[2];
    const float* b0 = (const float*)d_in[3];
    const float* W1 = (const float*)d_in[4];
    const float* b1 = (const float*)d_in[5];
    const float* W2 = (const float*)d_in[6];
    const float* b2 = (const float*)d_in[7];
    const float* Wo = (const float*)d_in[8];
    const float* bo = (const float*)d_in[9];
    float* out = (float*)d_out;

    char* ws = (char*)d_ws;
    unsigned int* bits    = (unsigned int*)(ws + 0);                  // 2 MB
    unsigned short* cols  = (unsigned short*)(ws + 2097152);          // 4 MB (uint16)
    int*   deg            = (int*)(ws + 6291456);                     // 16 KB
    unsigned short* xb    = (unsigned short*)(ws + 6307840);          // 8 MB
    unsigned short* ubuf  = (unsigned short*)(ws + 14696448);         // 8 MB
    unsigned short* Wt1a  = (unsigned short*)(ws + 23085056);
    unsigned short* Wt1b  = (unsigned short*)(ws + 23085056 + 32768);
    unsigned short* Wt2   = (unsigned short*)(ws + 23085056 + 65536);
    unsigned short* Wto   = (unsigned short*)(ws + 23085056 + 98304);
    unsigned short* W0bf  = (unsigned short*)(ws + 23085056 + 131072);
    unsigned short* Wtu   = (unsigned short*)(ws + 23085056 + 163840);
    float* c1             = (float*)(ws + 23085056 + 196608);

    k_init<<<2880, 256, 0, stream>>>((uint4*)bits, x, xb, W0, W1, W2, Wo,
                                     Wt1a, Wt1b, Wt2, Wto, W0bf);
    k_scatter<<<513, 256, 0, stream>>>(ei, bits, W0bf, Wt1b, b0, W1, Wtu, c1);
    k_csr<<<NN, 128, 0, stream>>>(bits, cols, deg);
    k_agg<<<BB * (NN / 4), 256, 0, stream>>>(xb, cols, deg, ubuf);
    k_mlp<<<M_ROWS / 64, 256, 0, stream>>>(xb, ubuf, Wt1a, Wtu, Wt2, Wto,
                                           c1, b1, b2, bo, deg, out);
}